// Round 4
// baseline (11064.926 us; speedup 1.0000x reference)
//
#include <hip/hip_runtime.h>
#include <stdint.h>

// ---------------------------------------------------------------------------
// Types / helpers
// ---------------------------------------------------------------------------
typedef short short8 __attribute__((ext_vector_type(8)));
typedef float float4v __attribute__((ext_vector_type(4)));

__device__ __forceinline__ float b2f(short s) {
    return __uint_as_float(((unsigned)(unsigned short)s) << 16);
}
__device__ __forceinline__ short f2b(float f) {
    unsigned u = __float_as_uint(f);
    unsigned r = (u + 0x7fffu + ((u >> 16) & 1u)) >> 16;
    return (short)r;
}

// ---------------------------------------------------------------------------
// fp32 -> bf16 convert (grid-stride)
// ---------------------------------------------------------------------------
__global__ void k_f32_to_bf16(const float* __restrict__ in, short* __restrict__ out, int n) {
    int i = blockIdx.x * blockDim.x + threadIdx.x;
    int stride = gridDim.x * blockDim.x;
    for (; i < n; i += stride) out[i] = f2b(in[i]);
}

// Fused converter for the 8 contiguous weight buffers (dst = ws base, element
// offsets fixed): w1(256K) w2(256K) wq(512K) wk(512K) wv(1M) wp(1M) wih(2M) whh(4M)
__global__ void k_cvt_weights(const float* __restrict__ s0, const float* __restrict__ s1,
                              const float* __restrict__ s2, const float* __restrict__ s3,
                              const float* __restrict__ s4, const float* __restrict__ s5,
                              const float* __restrict__ s6, const float* __restrict__ s7,
                              short* __restrict__ dst) {
    int i = blockIdx.x * blockDim.x + threadIdx.x;
    int stride = gridDim.x * blockDim.x;
    for (; i < 9961472; i += stride) {
        float v;
        if      (i <  262144) v = s0[i];
        else if (i <  524288) v = s1[i -  262144];
        else if (i < 1048576) v = s2[i -  524288];
        else if (i < 1572864) v = s3[i - 1048576];
        else if (i < 2621440) v = s4[i - 1572864];
        else if (i < 3670016) v = s5[i - 2621440];
        else if (i < 5767168) v = s6[i - 3670016];
        else                  v = s7[i - 5767168];
        dst[i] = f2b(v);
    }
}

// w_c1 [512][1024][3] -> bf16 [512][3*1024] with W'[c][dk*1024+h] = w_c1[c][h][dk]
__global__ void k_wc1_tr(const float* __restrict__ in, short* __restrict__ out) {
    int i = blockIdx.x * blockDim.x + threadIdx.x;
    if (i >= 512 * 3072) return;
    int c = i / 3072, rr = i % 3072, dk = rr / 1024, h = rr % 1024;
    out[i] = f2b(in[(c * 1024 + h) * 3 + dk]);
}

__global__ void k_bias_sum(const float* __restrict__ a, const float* __restrict__ b,
                           float* __restrict__ o, int n) {
    int i = blockIdx.x * blockDim.x + threadIdx.x;
    if (i < n) o[i] = a[i] + b[i];
}

// ---------------------------------------------------------------------------
// Generic batched GEMM:  C[m][n] = act( sum_k A[m][k]*B[n][k] + bias[n] )
// ---------------------------------------------------------------------------
__global__ __launch_bounds__(256) void k_gemm_bt(
    const short* __restrict__ A, const short* __restrict__ B,
    float* __restrict__ Cf, short* __restrict__ Cb,
    const float* __restrict__ bias,
    int M, int N, int K, int lda, int ldb, int ldc,
    int z0n, long sA0, long sA1, long sB0, long sB1, long sC0, long sC1,
    int act, int gap)
{
    __shared__ __align__(16) short lds[2 * 128 * 32];   // A chunks [0..511], B [512..1023]
    const int z = blockIdx.z;
    const int z0 = z % z0n, z1 = z / z0n;
    A += z1 * sA1 + z0 * sA0;
    B += z1 * sB1 + z0 * sB0;
    const long coff = z1 * sC1 + z0 * sC0;
    const int tn0 = blockIdx.x * 128, tm0 = blockIdx.y * 128;
    const int tid = threadIdx.x, ln = tid & 63, wv = tid >> 6;
    const int wr = wv >> 1, wc = wv & 1;

    float4v acc[4][4];
#pragma unroll
    for (int i = 0; i < 4; ++i)
#pragma unroll
        for (int j = 0; j < 4; ++j) acc[i][j] = (float4v){0.f, 0.f, 0.f, 0.f};

    const int nk = K >> 5;
    for (int kt = 0; kt < nk; ++kt) {
        __syncthreads();
#pragma unroll
        for (int s = 0; s < 4; ++s) {
            int p = tid + (s << 8);
            int pp = p & 511;
            int row = pp >> 2;
            int gcol = (pp & 3) ^ ((pp >> 3) & 3);
            short8 val;
            if (p < 512) {
                long grow = (long)(tm0 + row);
                if (gap) grow += 2 * (grow >> 10);
                val = *(const short8*)&A[grow * (long)lda + kt * 32 + gcol * 8];
            } else {
                val = *(const short8*)&B[(long)(tn0 + row) * ldb + kt * 32 + gcol * 8];
            }
            ((short8*)lds)[(p < 512 ? 0 : 512) + pp] = val;
        }
        __syncthreads();

        short8 af[4], bf_[4];
        const int q = ln >> 4;
#pragma unroll
        for (int i = 0; i < 4; ++i) {
            int r = wr * 64 + i * 16 + (ln & 15);
            af[i] = ((short8*)lds)[r * 4 + (q ^ ((r >> 1) & 3))];
        }
#pragma unroll
        for (int j = 0; j < 4; ++j) {
            int r = wc * 64 + j * 16 + (ln & 15);
            bf_[j] = ((short8*)lds)[512 + r * 4 + (q ^ ((r >> 1) & 3))];
        }
#pragma unroll
        for (int i = 0; i < 4; ++i)
#pragma unroll
            for (int j = 0; j < 4; ++j)
                acc[i][j] = __builtin_amdgcn_mfma_f32_16x16x32_bf16(af[i], bf_[j], acc[i][j], 0, 0, 0);
    }

    // epilogue: D[row=(l>>4)*4+reg][col=l&15]
#pragma unroll
    for (int j = 0; j < 4; ++j) {
        int nglob = tn0 + wc * 64 + j * 16 + (ln & 15);
        float bv = bias ? bias[nglob] : 0.f;
#pragma unroll
        for (int i = 0; i < 4; ++i) {
#pragma unroll
            for (int r = 0; r < 4; ++r) {
                int mglob = tm0 + wr * 64 + i * 16 + (ln >> 4) * 4 + r;
                float v = acc[i][j][r] + bv;
                if (act == 1) v = (v >= 0.f) ? v : 0.25f * v;
                else if (act == 2) v = fmaxf(v, 0.f);
                long ci = coff + (long)mglob * ldc + nglob;
                if (Cf) Cf[ci] = v;
                if (Cb) Cb[ci] = f2b(v);
            }
        }
    }
}

// ---------------------------------------------------------------------------
// Row softmax over 1024, bf16 in-place
// ---------------------------------------------------------------------------
__global__ __launch_bounds__(256) void k_softmax_rows_bf16(short* __restrict__ p) {
    long row = blockIdx.x;
    short* r = p + (row << 10);
    int tid = threadIdx.x;
    float v[4];
    float mx = -3.4e38f;
#pragma unroll
    for (int i = 0; i < 4; ++i) { v[i] = b2f(r[tid + (i << 8)]); mx = fmaxf(mx, v[i]); }
#pragma unroll
    for (int d = 32; d > 0; d >>= 1) mx = fmaxf(mx, __shfl_down(mx, d));
    __shared__ float red[4], red2[4];
    if ((tid & 63) == 0) red[tid >> 6] = mx;
    __syncthreads();
    mx = fmaxf(fmaxf(red[0], red[1]), fmaxf(red[2], red[3]));
    float s = 0.f;
#pragma unroll
    for (int i = 0; i < 4; ++i) { v[i] = expf(v[i] - mx); s += v[i]; }
#pragma unroll
    for (int d = 32; d > 0; d >>= 1) s += __shfl_down(s, d);
    if ((tid & 63) == 0) red2[tid >> 6] = s;
    __syncthreads();
    s = red2[0] + red2[1] + red2[2] + red2[3];
    float inv = 1.f / s;
#pragma unroll
    for (int i = 0; i < 4; ++i) r[tid + (i << 8)] = f2b(v[i] * inv);
}

// fp32 softmax over T=1024, in place
__global__ __launch_bounds__(256) void k_softmax_rows_f32(float* __restrict__ p) {
    long row = blockIdx.x;
    float* r = p + (row << 10);
    int tid = threadIdx.x;
    float v[4];
    float mx = -3.4e38f;
#pragma unroll
    for (int i = 0; i < 4; ++i) { v[i] = r[tid + (i << 8)]; mx = fmaxf(mx, v[i]); }
#pragma unroll
    for (int d = 32; d > 0; d >>= 1) mx = fmaxf(mx, __shfl_down(mx, d));
    __shared__ float red[4], red2[4];
    if ((tid & 63) == 0) red[tid >> 6] = mx;
    __syncthreads();
    mx = fmaxf(fmaxf(red[0], red[1]), fmaxf(red[2], red[3]));
    float s = 0.f;
#pragma unroll
    for (int i = 0; i < 4; ++i) { v[i] = expf(v[i] - mx); s += v[i]; }
#pragma unroll
    for (int d = 32; d > 0; d >>= 1) s += __shfl_down(s, d);
    if ((tid & 63) == 0) red2[tid >> 6] = s;
    __syncthreads();
    s = red2[0] + red2[1] + red2[2] + red2[3];
    float inv = 1.f / s;
#pragma unroll
    for (int i = 0; i < 4; ++i) r[tid + (i << 8)] = v[i] * inv;
}

// ---------------------------------------------------------------------------
// LayerNorm over E=512 (bf16 in -> bf16 out), rows = 8192
// ---------------------------------------------------------------------------
__global__ __launch_bounds__(256) void k_layernorm(const short* __restrict__ y,
                                                   const float* __restrict__ gam,
                                                   const float* __restrict__ bet,
                                                   short* __restrict__ o) {
    const long row = blockIdx.x;
    const short* r = y + (row << 9);
    const int tid = threadIdx.x;
    float v0 = b2f(r[tid]), v1 = b2f(r[tid + 256]);
    float s = v0 + v1, ss = v0 * v0 + v1 * v1;
#pragma unroll
    for (int d = 32; d > 0; d >>= 1) { s += __shfl_down(s, d); ss += __shfl_down(ss, d); }
    __shared__ float rs_[4], rss[4];
    if ((tid & 63) == 0) { rs_[tid >> 6] = s; rss[tid >> 6] = ss; }
    __syncthreads();
    s = rs_[0] + rs_[1] + rs_[2] + rs_[3];
    ss = rss[0] + rss[1] + rss[2] + rss[3];
    float mean = s * (1.f / 512.f);
    float var = ss * (1.f / 512.f) - mean * mean;
    float rstd = rsqrtf(var + 1e-5f);
    short* out = o + (row << 9);
    out[tid]       = f2b((v0 - mean) * rstd * gam[tid]       + bet[tid]);
    out[tid + 256] = f2b((v1 - mean) * rstd * gam[tid + 256] + bet[tid + 256]);
}

// ---------------------------------------------------------------------------
// v [8192][2048] -> vT [32][512][1024] ([bn][d][s])
// ---------------------------------------------------------------------------
__global__ __launch_bounds__(256) void k_vT(const short* __restrict__ v, short* __restrict__ vT) {
    __shared__ short t[32][34];
    int bn = blockIdx.z, b = bn >> 2, n = bn & 3;
    int s0 = blockIdx.y * 32, d0 = blockIdx.x * 32;
    int lx = threadIdx.x & 31, ly = threadIdx.x >> 5;
#pragma unroll
    for (int i = 0; i < 4; ++i) {
        int s = ly + i * 8;
        t[s][lx] = v[(long)(b * 1024 + s0 + s) * 2048 + n * 512 + d0 + lx];
    }
    __syncthreads();
#pragma unroll
    for (int i = 0; i < 4; ++i) {
        int d = ly + i * 8;
        vT[((long)bn * 512 + d0 + d) * 1024 + s0 + lx] = t[lx][d];
    }
}

// ---------------------------------------------------------------------------
// Persistent LSTM with SELF-FLAGGING h exchange: each h value is a 32-bit
// word {bf16 h <<16 | step tag}. Consumers poll the tagged data directly —
// no flags, no producer ack wait, no flag-propagation hop. Double buffer by
// step parity (2 generations provably sufficient for all-to-all dependency).
// All cross-block ops relaxed agent-scope (IC-coherent, no cache maint).
// ---------------------------------------------------------------------------
__global__ __launch_bounds__(256) void k_lstm(
    const short* __restrict__ whh, const short* __restrict__ igb,
    unsigned int* __restrict__ ht,      // [2][8][1024] tagged h
    short* __restrict__ lstm_pad)
{
    const int g = blockIdx.x;            // 0..127
    const int tid = threadIdx.x;
    const int ln = tid & 63, wv = tid >> 6;
    const int kbase = wv * 256 + ((ln >> 4) << 3);

    // preload w_hh fragments: B-frag lane ln holds W[n][k], n = nt*16+(ln&15)
    short8 wf[2][8];
#pragma unroll
    for (int nt = 0; nt < 2; ++nt) {
        int n = nt * 16 + (ln & 15);
        int q = n >> 3, r = n & 7;
        long row = (long)q * 1024 + g * 8 + r;
#pragma unroll
        for (int kk = 0; kk < 8; ++kk)
            wf[nt][kk] = *(const short8*)&whh[row * 1024 + kbase + kk * 32];
    }

    __shared__ float part[4][16][33];
    const int gm = tid >> 3, gu = tid & 7;   // gate lanes = wave 0 (tid<64)
    float c_prev = 0.f;
    const int arow = ln & 15;
    const bool act8 = (arow < 8);

    // prefetch ig for step 0
    float igv[4];
    if (tid < 64) {
#pragma unroll
        for (int qq = 0; qq < 4; ++qq)
            igv[qq] = b2f(igb[((long)gm * 1024 + 0) * 4096 + qq * 1024 + g * 8 + gu]);
    }

    unsigned int w[8][8];

    for (int step = 0; step < 1024; ++step) {
        const unsigned tag = (unsigned)step;
        const unsigned int* hw = ht + ((step & 1) << 13) + (arow << 10) + kbase;

        // ---- poll tagged h until this wave's full fragment has arrived ----
        if (act8) {
#pragma unroll
            for (int kk = 0; kk < 8; ++kk)
#pragma unroll
                for (int j = 0; j < 8; ++j)
                    w[kk][j] = __hip_atomic_load(hw + kk * 32 + j,
                                                 __ATOMIC_RELAXED, __HIP_MEMORY_SCOPE_AGENT);
        }
        while (true) {
            unsigned bad = 0;
            if (act8) {
#pragma unroll
                for (int kk = 0; kk < 8; ++kk)
#pragma unroll
                    for (int j = 0; j < 8; ++j)
                        bad |= (w[kk][j] ^ tag) & 0xffffu;
            }
            if (__all(bad == 0)) break;
            __builtin_amdgcn_s_sleep(1);
            if (act8) {
#pragma unroll
                for (int kk = 0; kk < 8; ++kk)
#pragma unroll
                    for (int j = 0; j < 8; ++j)
                        w[kk][j] = __hip_atomic_load(hw + kk * 32 + j,
                                                     __ATOMIC_RELAXED, __HIP_MEMORY_SCOPE_AGENT);
            }
        }

        // unpack h (high 16 bits) into MFMA A-fragments
        short8 af[8];
#pragma unroll
        for (int kk = 0; kk < 8; ++kk)
#pragma unroll
            for (int j = 0; j < 8; ++j)
                af[kk][j] = act8 ? (short)(w[kk][j] >> 16) : (short)0;

        float4v acc0 = (float4v){0.f, 0.f, 0.f, 0.f};
        float4v acc1 = (float4v){0.f, 0.f, 0.f, 0.f};
#pragma unroll
        for (int kk = 0; kk < 8; ++kk) {
            acc0 = __builtin_amdgcn_mfma_f32_16x16x32_bf16(af[kk], wf[0][kk], acc0, 0, 0, 0);
            acc1 = __builtin_amdgcn_mfma_f32_16x16x32_bf16(af[kk], wf[1][kk], acc1, 0, 0, 0);
        }
#pragma unroll
        for (int rr = 0; rr < 4; ++rr) {
            part[wv][(ln >> 4) * 4 + rr][ln & 15]        = acc0[rr];
            part[wv][(ln >> 4) * 4 + rr][16 + (ln & 15)] = acc1[rr];
        }
        __syncthreads();

        // gate lanes read partials into regs, then release LDS for next step
        float psum[4];
        if (tid < 64) {
#pragma unroll
            for (int qq = 0; qq < 4; ++qq) {
                int nn = qq * 8 + gu;
                psum[qq] = part[0][gm][nn] + part[1][gm][nn] + part[2][gm][nn] + part[3][gm][nn];
            }
        }
        __syncthreads();

        if (tid < 64) {
            float g0 = psum[0] + igv[0];
            float g1 = psum[1] + igv[1];
            float g2 = psum[2] + igv[2];
            float g3 = psum[3] + igv[3];
            float iv = 1.f / (1.f + __expf(-g0));
            float fv = 1.f / (1.f + __expf(-g1));
            float gv = 2.f / (1.f + __expf(-2.f * g2)) - 1.f;
            float ov = 1.f / (1.f + __expf(-g3));
            float c = fv * c_prev + iv * gv;
            c_prev = c;
            float h = ov * (2.f / (1.f + __expf(-2.f * c)) - 1.f);
            short hb16 = f2b(h);
            unsigned word = ((unsigned)(unsigned short)hb16 << 16) | (unsigned)(step + 1);
            __hip_atomic_store(ht + (((step + 1) & 1) << 13) + (gm << 10) + g * 8 + gu,
                               word, __ATOMIC_RELAXED, __HIP_MEMORY_SCOPE_AGENT);
            lstm_pad[((long)gm * 1026 + step + 1) * 1024 + g * 8 + gu] = hb16;
            if (step + 1 < 1024) {
#pragma unroll
                for (int qq = 0; qq < 4; ++qq)
                    igv[qq] = b2f(igb[((long)gm * 1024 + step + 1) * 4096 + qq * 1024 + g * 8 + gu]);
            }
        }
    }
}

// ---------------------------------------------------------------------------
// conv2: a1 [8192][512] bf16 (relu'd), w [2][512][3], out a2 [8][2][1024] fp32
// ---------------------------------------------------------------------------
__global__ __launch_bounds__(256) void k_conv2(const short* __restrict__ a1,
                                               const float* __restrict__ w,
                                               const float* __restrict__ bias,
                                               float* __restrict__ a2) {
    int idx = blockIdx.x * blockDim.x + threadIdx.x;    // (b*2+c)*1024+t
    if (idx >= 8 * 2 * 1024) return;
    int t = idx & 1023, c = (idx >> 10) & 1, b = idx >> 11;
    float s = bias[c];
    for (int dk = 0; dk < 3; ++dk) {
        int tt = t + dk - 1;
        if (tt < 0 || tt >= 1024) continue;
        const short* arow = a1 + (long)(b * 1024 + tt) * 512;
        const float* wrow = w + c * 1536 + dk;
        for (int j = 0; j < 512; ++j) s += b2f(arow[j]) * wrow[j * 3];
    }
    a2[idx] = s;
}

// ---------------------------------------------------------------------------
// feat[b][c][h] = sum_t attw[(b*2+c)*1024+t] * lstm_pad[b][t+1][h]
// ---------------------------------------------------------------------------
__global__ __launch_bounds__(256) void k_feat(const float* __restrict__ attw,
                                              const short* __restrict__ lstm_pad,
                                              float* __restrict__ out) {
    int bc = blockIdx.x;        // 0..15
    int b = bc >> 1;
    int tid = threadIdx.x;
    __shared__ float aw[1024];
    for (int i = tid; i < 1024; i += 256) aw[i] = attw[bc * 1024 + i];
    __syncthreads();
    float acc[4] = {0.f, 0.f, 0.f, 0.f};
    for (int t = 0; t < 1024; ++t) {
        float a = aw[t];
        const short* hrow = lstm_pad + ((long)(b * 1026 + t + 1)) * 1024;
#pragma unroll
        for (int i = 0; i < 4; ++i) acc[i] += a * b2f(hrow[tid + (i << 8)]);
    }
#pragma unroll
    for (int i = 0; i < 4; ++i) out[bc * 1024 + tid + (i << 8)] = acc[i];
}

// ---------------------------------------------------------------------------
// Host orchestration
// ---------------------------------------------------------------------------
static void gemm_bt(hipStream_t st, const short* A, const short* B, float* Cf, short* Cb,
                    const float* bias, int M, int N, int K, int lda, int ldb, int ldc,
                    int z, int z0n, long sA0, long sA1, long sB0, long sB1, long sC0, long sC1,
                    int act, int gap) {
    dim3 grid(N / 128, M / 128, z);
    k_gemm_bt<<<grid, dim3(256), 0, st>>>(A, B, Cf, Cb, bias, M, N, K, lda, ldb, ldc,
                                          z0n, sA0, sA1, sB0, sB1, sC0, sC1, act, gap);
}

extern "C" void kernel_launch(void* const* d_in, const int* in_sizes, int n_in,
                              void* d_out, int out_size, void* d_ws, size_t ws_size,
                              hipStream_t stream) {
    if (ws_size < 199409920u) return;

    const float* x     = (const float*)d_in[0];
    const float* w_in1 = (const float*)d_in[1];
    const float* b_in1 = (const float*)d_in[2];
    const float* w_in2 = (const float*)d_in[3];
    const float* b_in2 = (const float*)d_in[4];
    const float* w_q   = (const float*)d_in[5];
    const float* b_q   = (const float*)d_in[6];
    const float* w_k   = (const float*)d_in[7];
    const float* b_k   = (const float*)d_in[8];
    const float* w_v   = (const float*)d_in[9];
    const float* b_v   = (const float*)d_in[10];
    const float* w_p   = (const float*)d_in[11];
    const float* b_p   = (const float*)d_in[12];
    const float* ln_g  = (const float*)d_in[13];
    const float* ln_b  = (const float*)d_in[14];
    const float* w_ih  = (const float*)d_in[15];
    const float* w_hh  = (const float*)d_in[16];
    const float* b_ih  = (const float*)d_in[17];
    const float* b_hh  = (const float*)d_in[18];
    const float* w_c1  = (const float*)d_in[19];
    const float* b_c1  = (const float*)d_in[20];
    const float* w_c2  = (const float*)d_in[21];
    const float* b_c2  = (const float*)d_in[22];

    char* ws = (char*)d_ws;
    // ---- static region ----
    short* w1b  = (short*)(ws + 0);
    short* wihb = (short*)(ws + 7340032);
    short* wc1b = (short*)(ws + 19922944);
    float* bsum = (float*)(ws + 23068672);
    unsigned int* ht = (unsigned int*)(ws + 23085056);   // [2][8][1024] tagged h, 64 KB
    float* a2   = (float*)(ws + 23150848);
    short* lpad = (short*)(ws + 23216384);
    short* w2b  = (short*)(ws + 524288);
    short* wqb  = (short*)(ws + 1048576);
    short* wkb  = (short*)(ws + 2097152);
    short* wvb  = (short*)(ws + 3145728);
    short* wpb  = (short*)(ws + 5242880);
    short* whhb = (short*)(ws + 11534336);
    // ---- dynamic region D0 = 40,026,368 ----
    const size_t D0 = 40026368u;
    short* xbf   = (short*)(ws + D0);
    short* h1bf  = (short*)(ws + D0 + 8388608);
    short* h2bf  = (short*)(ws + D0 + 16777216);
    short* qbf   = (short*)(ws + D0 + 25165824);
    short* kbf   = (short*)(ws + D0 + 41943040);
    short* vbf   = (short*)(ws + D0 + 58720256);
    short* vTbf  = (short*)(ws + D0 + 92274688);
    short* scb   = (short*)(ws + D0);                 // 16 MB (xbf+h1bf slots, dead)
    short* obf   = (short*)(ws + D0 + 125829120);
    short* ybf   = (short*)(ws + D0 + 58720256);
    short* ylnbf = (short*)(ws + D0 + 67108864);
    short* igb   = (short*)(ws + D0 + 92274688);
    short* a1bf  = (short*)(ws + D0);

    hipMemsetAsync(lpad, 0, (size_t)8 * 1026 * 1024 * 2, stream);
    hipMemsetAsync(ht, 0, 65536, stream);   // tag 0 == step-0 h (zeros)

    k_f32_to_bf16<<<dim3(4096), dim3(256), 0, stream>>>(x, xbf, 8192 * 512);
    k_cvt_weights<<<dim3(4096), dim3(256), 0, stream>>>(w_in1, w_in2, w_q, w_k, w_v, w_p,
                                                        w_ih, w_hh, w1b);
    k_wc1_tr<<<dim3((512 * 3072 + 255) / 256), dim3(256), 0, stream>>>(w_c1, wc1b);
    k_bias_sum<<<dim3(16), dim3(256), 0, stream>>>(b_ih, b_hh, bsum, 4096);

    gemm_bt(stream, xbf, w1b, nullptr, h1bf, b_in1, 8192, 512, 512, 512, 512, 512,
            1, 1, 0, 0, 0, 0, 0, 0, 1, 0);
    gemm_bt(stream, h1bf, w2b, nullptr, h2bf, b_in2, 8192, 512, 512, 512, 512, 512,
            1, 1, 0, 0, 0, 0, 0, 0, 0, 0);
    gemm_bt(stream, h2bf, wqb, nullptr, qbf, b_q, 8192, 1024, 512, 512, 512, 1024,
            1, 1, 0, 0, 0, 0, 0, 0, 0, 0);
    gemm_bt(stream, h2bf, wkb, nullptr, kbf, b_k, 8192, 1024, 512, 512, 512, 1024,
            1, 1, 0, 0, 0, 0, 0, 0, 0, 0);
    gemm_bt(stream, h2bf, wvb, nullptr, vbf, b_v, 8192, 2048, 512, 512, 512, 2048,
            1, 1, 0, 0, 0, 0, 0, 0, 0, 0);
    k_vT<<<dim3(16, 32, 32), dim3(256), 0, stream>>>(vbf, vTbf);

    // attention: 2 batches per iteration (z = 2 batches x 4 heads)
    for (int bg = 0; bg < 4; ++bg) {
        const short* qb = qbf + (long)bg * 2097152;
        const short* kb = kbf + (long)bg * 2097152;
        gemm_bt(stream, qb, kb, nullptr, scb, nullptr, 1024, 1024, 256, 1024, 1024, 1024,
                8, 4, 256, 1048576, 256, 1048576, 1048576, 4194304, 0, 0);
        k_softmax_rows_bf16<<<dim3(8192), dim3(256), 0, stream>>>(scb);
        gemm_bt(stream, scb, vTbf + (long)bg * 4194304, nullptr, obf + (long)bg * 4194304, nullptr,
                1024, 512, 1024, 1024, 1024, 2048,
                8, 4, 1048576, 4194304, 524288, 2097152, 512, 2097152, 0, 0);
    }

    gemm_bt(stream, obf, wpb, nullptr, ybf, b_p, 8192, 512, 2048, 2048, 2048, 512,
            1, 1, 0, 0, 0, 0, 0, 0, 0, 0);
    k_layernorm<<<dim3(8192), dim3(256), 0, stream>>>(ybf, ln_g, ln_b, ylnbf);
    gemm_bt(stream, ylnbf, wihb, nullptr, igb, bsum, 8192, 4096, 512, 512, 512, 4096,
            1, 1, 0, 0, 0, 0, 0, 0, 0, 0);
    k_lstm<<<dim3(128), dim3(256), 0, stream>>>(whhb, igb, ht, lpad);
    gemm_bt(stream, lpad, wc1b, nullptr, a1bf, b_c1, 8192, 512, 3072, 1024, 3072, 512,
            1, 1, 0, 0, 0, 0, 0, 0, 2, 1);
    k_conv2<<<dim3(64), dim3(256), 0, stream>>>(a1bf, w_c2, b_c2, a2);
    k_softmax_rows_f32<<<dim3(16), dim3(256), 0, stream>>>(a2);
    k_feat<<<dim3(16), dim3(256), 0, stream>>>(a2, lpad, (float*)d_out);
    (void)in_sizes; (void)n_in; (void)out_size; (void)ws_size;
}

// Round 5
// 6983.073 us; speedup vs baseline: 1.5845x; 1.5845x over previous
//
#include <hip/hip_runtime.h>
#include <stdint.h>

// ---------------------------------------------------------------------------
// Types / helpers
// ---------------------------------------------------------------------------
typedef short short8 __attribute__((ext_vector_type(8)));
typedef float float4v __attribute__((ext_vector_type(4)));
typedef unsigned int uint4v __attribute__((ext_vector_type(4)));

__device__ __forceinline__ float b2f(short s) {
    return __uint_as_float(((unsigned)(unsigned short)s) << 16);
}
__device__ __forceinline__ short f2b(float f) {
    unsigned u = __float_as_uint(f);
    unsigned r = (u + 0x7fffu + ((u >> 16) & 1u)) >> 16;
    return (short)r;
}

// 8x dwordx4 tagged-h poll loads. Fast: sc0 (L1 bypass, shared-L2 hit).
// Coherent: sc0 sc1 (L2 bypass, IC truth) — escalation/correctness path.
__device__ __forceinline__ void load8_fast(const unsigned* a,
    uint4v& w0, uint4v& w1, uint4v& w2, uint4v& w3,
    uint4v& w4, uint4v& w5, uint4v& w6, uint4v& w7) {
    asm volatile(
        "global_load_dwordx4 %0, %8, off sc0\n\t"
        "global_load_dwordx4 %1, %8, off offset:16 sc0\n\t"
        "global_load_dwordx4 %2, %8, off offset:128 sc0\n\t"
        "global_load_dwordx4 %3, %8, off offset:144 sc0\n\t"
        "global_load_dwordx4 %4, %8, off offset:256 sc0\n\t"
        "global_load_dwordx4 %5, %8, off offset:272 sc0\n\t"
        "global_load_dwordx4 %6, %8, off offset:384 sc0\n\t"
        "global_load_dwordx4 %7, %8, off offset:400 sc0\n\t"
        "s_waitcnt vmcnt(0)"
        : "=v"(w0), "=v"(w1), "=v"(w2), "=v"(w3),
          "=v"(w4), "=v"(w5), "=v"(w6), "=v"(w7)
        : "v"(a) : "memory");
}
__device__ __forceinline__ void load8_coh(const unsigned* a,
    uint4v& w0, uint4v& w1, uint4v& w2, uint4v& w3,
    uint4v& w4, uint4v& w5, uint4v& w6, uint4v& w7) {
    asm volatile(
        "global_load_dwordx4 %0, %8, off sc0 sc1\n\t"
        "global_load_dwordx4 %1, %8, off offset:16 sc0 sc1\n\t"
        "global_load_dwordx4 %2, %8, off offset:128 sc0 sc1\n\t"
        "global_load_dwordx4 %3, %8, off offset:144 sc0 sc1\n\t"
        "global_load_dwordx4 %4, %8, off offset:256 sc0 sc1\n\t"
        "global_load_dwordx4 %5, %8, off offset:272 sc0 sc1\n\t"
        "global_load_dwordx4 %6, %8, off offset:384 sc0 sc1\n\t"
        "global_load_dwordx4 %7, %8, off offset:400 sc0 sc1\n\t"
        "s_waitcnt vmcnt(0)"
        : "=v"(w0), "=v"(w1), "=v"(w2), "=v"(w3),
          "=v"(w4), "=v"(w5), "=v"(w6), "=v"(w7)
        : "v"(a) : "memory");
}
__device__ __forceinline__ short8 unpack2(uint4v lo, uint4v hi) {
    short8 o;
    o[0] = (short)(lo[0] >> 16); o[1] = (short)(lo[1] >> 16);
    o[2] = (short)(lo[2] >> 16); o[3] = (short)(lo[3] >> 16);
    o[4] = (short)(hi[0] >> 16); o[5] = (short)(hi[1] >> 16);
    o[6] = (short)(hi[2] >> 16); o[7] = (short)(hi[3] >> 16);
    return o;
}

// ---------------------------------------------------------------------------
// fp32 -> bf16 convert (grid-stride)
// ---------------------------------------------------------------------------
__global__ void k_f32_to_bf16(const float* __restrict__ in, short* __restrict__ out, int n) {
    int i = blockIdx.x * blockDim.x + threadIdx.x;
    int stride = gridDim.x * blockDim.x;
    for (; i < n; i += stride) out[i] = f2b(in[i]);
}

// Fused converter for the 8 contiguous weight buffers
__global__ void k_cvt_weights(const float* __restrict__ s0, const float* __restrict__ s1,
                              const float* __restrict__ s2, const float* __restrict__ s3,
                              const float* __restrict__ s4, const float* __restrict__ s5,
                              const float* __restrict__ s6, const float* __restrict__ s7,
                              short* __restrict__ dst) {
    int i = blockIdx.x * blockDim.x + threadIdx.x;
    int stride = gridDim.x * blockDim.x;
    for (; i < 9961472; i += stride) {
        float v;
        if      (i <  262144) v = s0[i];
        else if (i <  524288) v = s1[i -  262144];
        else if (i < 1048576) v = s2[i -  524288];
        else if (i < 1572864) v = s3[i - 1048576];
        else if (i < 2621440) v = s4[i - 1572864];
        else if (i < 3670016) v = s5[i - 2621440];
        else if (i < 5767168) v = s6[i - 3670016];
        else                  v = s7[i - 5767168];
        dst[i] = f2b(v);
    }
}

// w_c1 [512][1024][3] -> bf16 [512][3*1024]
__global__ void k_wc1_tr(const float* __restrict__ in, short* __restrict__ out) {
    int i = blockIdx.x * blockDim.x + threadIdx.x;
    if (i >= 512 * 3072) return;
    int c = i / 3072, rr = i % 3072, dk = rr / 1024, h = rr % 1024;
    out[i] = f2b(in[(c * 1024 + h) * 3 + dk]);
}

__global__ void k_bias_sum(const float* __restrict__ a, const float* __restrict__ b,
                           float* __restrict__ o, int n) {
    int i = blockIdx.x * blockDim.x + threadIdx.x;
    if (i < n) o[i] = a[i] + b[i];
}

// ---------------------------------------------------------------------------
// Generic batched GEMM:  C[m][n] = act( sum_k A[m][k]*B[n][k] + bias[n] )
// ---------------------------------------------------------------------------
__global__ __launch_bounds__(256) void k_gemm_bt(
    const short* __restrict__ A, const short* __restrict__ B,
    float* __restrict__ Cf, short* __restrict__ Cb,
    const float* __restrict__ bias,
    int M, int N, int K, int lda, int ldb, int ldc,
    int z0n, long sA0, long sA1, long sB0, long sB1, long sC0, long sC1,
    int act, int gap)
{
    __shared__ __align__(16) short lds[2 * 128 * 32];
    const int z = blockIdx.z;
    const int z0 = z % z0n, z1 = z / z0n;
    A += z1 * sA1 + z0 * sA0;
    B += z1 * sB1 + z0 * sB0;
    const long coff = z1 * sC1 + z0 * sC0;
    const int tn0 = blockIdx.x * 128, tm0 = blockIdx.y * 128;
    const int tid = threadIdx.x, ln = tid & 63, wv = tid >> 6;
    const int wr = wv >> 1, wc = wv & 1;

    float4v acc[4][4];
#pragma unroll
    for (int i = 0; i < 4; ++i)
#pragma unroll
        for (int j = 0; j < 4; ++j) acc[i][j] = (float4v){0.f, 0.f, 0.f, 0.f};

    const int nk = K >> 5;
    for (int kt = 0; kt < nk; ++kt) {
        __syncthreads();
#pragma unroll
        for (int s = 0; s < 4; ++s) {
            int p = tid + (s << 8);
            int pp = p & 511;
            int row = pp >> 2;
            int gcol = (pp & 3) ^ ((pp >> 3) & 3);
            short8 val;
            if (p < 512) {
                long grow = (long)(tm0 + row);
                if (gap) grow += 2 * (grow >> 10);
                val = *(const short8*)&A[grow * (long)lda + kt * 32 + gcol * 8];
            } else {
                val = *(const short8*)&B[(long)(tn0 + row) * ldb + kt * 32 + gcol * 8];
            }
            ((short8*)lds)[(p < 512 ? 0 : 512) + pp] = val;
        }
        __syncthreads();

        short8 af[4], bf_[4];
        const int q = ln >> 4;
#pragma unroll
        for (int i = 0; i < 4; ++i) {
            int r = wr * 64 + i * 16 + (ln & 15);
            af[i] = ((short8*)lds)[r * 4 + (q ^ ((r >> 1) & 3))];
        }
#pragma unroll
        for (int j = 0; j < 4; ++j) {
            int r = wc * 64 + j * 16 + (ln & 15);
            bf_[j] = ((short8*)lds)[512 + r * 4 + (q ^ ((r >> 1) & 3))];
        }
#pragma unroll
        for (int i = 0; i < 4; ++i)
#pragma unroll
            for (int j = 0; j < 4; ++j)
                acc[i][j] = __builtin_amdgcn_mfma_f32_16x16x32_bf16(af[i], bf_[j], acc[i][j], 0, 0, 0);
    }

#pragma unroll
    for (int j = 0; j < 4; ++j) {
        int nglob = tn0 + wc * 64 + j * 16 + (ln & 15);
        float bv = bias ? bias[nglob] : 0.f;
#pragma unroll
        for (int i = 0; i < 4; ++i) {
#pragma unroll
            for (int r = 0; r < 4; ++r) {
                int mglob = tm0 + wr * 64 + i * 16 + (ln >> 4) * 4 + r;
                float v = acc[i][j][r] + bv;
                if (act == 1) v = (v >= 0.f) ? v : 0.25f * v;
                else if (act == 2) v = fmaxf(v, 0.f);
                long ci = coff + (long)mglob * ldc + nglob;
                if (Cf) Cf[ci] = v;
                if (Cb) Cb[ci] = f2b(v);
            }
        }
    }
}

// ---------------------------------------------------------------------------
// Row softmax over 1024, bf16 in-place
// ---------------------------------------------------------------------------
__global__ __launch_bounds__(256) void k_softmax_rows_bf16(short* __restrict__ p) {
    long row = blockIdx.x;
    short* r = p + (row << 10);
    int tid = threadIdx.x;
    float v[4];
    float mx = -3.4e38f;
#pragma unroll
    for (int i = 0; i < 4; ++i) { v[i] = b2f(r[tid + (i << 8)]); mx = fmaxf(mx, v[i]); }
#pragma unroll
    for (int d = 32; d > 0; d >>= 1) mx = fmaxf(mx, __shfl_down(mx, d));
    __shared__ float red[4], red2[4];
    if ((tid & 63) == 0) red[tid >> 6] = mx;
    __syncthreads();
    mx = fmaxf(fmaxf(red[0], red[1]), fmaxf(red[2], red[3]));
    float s = 0.f;
#pragma unroll
    for (int i = 0; i < 4; ++i) { v[i] = expf(v[i] - mx); s += v[i]; }
#pragma unroll
    for (int d = 32; d > 0; d >>= 1) s += __shfl_down(s, d);
    if ((tid & 63) == 0) red2[tid >> 6] = s;
    __syncthreads();
    s = red2[0] + red2[1] + red2[2] + red2[3];
    float inv = 1.f / s;
#pragma unroll
    for (int i = 0; i < 4; ++i) r[tid + (i << 8)] = f2b(v[i] * inv);
}

// fp32 softmax over T=1024, in place
__global__ __launch_bounds__(256) void k_softmax_rows_f32(float* __restrict__ p) {
    long row = blockIdx.x;
    float* r = p + (row << 10);
    int tid = threadIdx.x;
    float v[4];
    float mx = -3.4e38f;
#pragma unroll
    for (int i = 0; i < 4; ++i) { v[i] = r[tid + (i << 8)]; mx = fmaxf(mx, v[i]); }
#pragma unroll
    for (int d = 32; d > 0; d >>= 1) mx = fmaxf(mx, __shfl_down(mx, d));
    __shared__ float red[4], red2[4];
    if ((tid & 63) == 0) red[tid >> 6] = mx;
    __syncthreads();
    mx = fmaxf(fmaxf(red[0], red[1]), fmaxf(red[2], red[3]));
    float s = 0.f;
#pragma unroll
    for (int i = 0; i < 4; ++i) { v[i] = expf(v[i] - mx); s += v[i]; }
#pragma unroll
    for (int d = 32; d > 0; d >>= 1) s += __shfl_down(s, d);
    if ((tid & 63) == 0) red2[tid >> 6] = s;
    __syncthreads();
    s = red2[0] + red2[1] + red2[2] + red2[3];
    float inv = 1.f / s;
#pragma unroll
    for (int i = 0; i < 4; ++i) r[tid + (i << 8)] = v[i] * inv;
}

// ---------------------------------------------------------------------------
// LayerNorm over E=512 (bf16 in -> bf16 out), rows = 8192
// ---------------------------------------------------------------------------
__global__ __launch_bounds__(256) void k_layernorm(const short* __restrict__ y,
                                                   const float* __restrict__ gam,
                                                   const float* __restrict__ bet,
                                                   short* __restrict__ o) {
    const long row = blockIdx.x;
    const short* r = y + (row << 9);
    const int tid = threadIdx.x;
    float v0 = b2f(r[tid]), v1 = b2f(r[tid + 256]);
    float s = v0 + v1, ss = v0 * v0 + v1 * v1;
#pragma unroll
    for (int d = 32; d > 0; d >>= 1) { s += __shfl_down(s, d); ss += __shfl_down(ss, d); }
    __shared__ float rs_[4], rss[4];
    if ((tid & 63) == 0) { rs_[tid >> 6] = s; rss[tid >> 6] = ss; }
    __syncthreads();
    s = rs_[0] + rs_[1] + rs_[2] + rs_[3];
    ss = rss[0] + rss[1] + rss[2] + rss[3];
    float mean = s * (1.f / 512.f);
    float var = ss * (1.f / 512.f) - mean * mean;
    float rstd = rsqrtf(var + 1e-5f);
    short* out = o + (row << 9);
    out[tid]       = f2b((v0 - mean) * rstd * gam[tid]       + bet[tid]);
    out[tid + 256] = f2b((v1 - mean) * rstd * gam[tid + 256] + bet[tid + 256]);
}

// ---------------------------------------------------------------------------
// v [8192][2048] -> vT [32][512][1024] ([bn][d][s])
// ---------------------------------------------------------------------------
__global__ __launch_bounds__(256) void k_vT(const short* __restrict__ v, short* __restrict__ vT) {
    __shared__ short t[32][34];
    int bn = blockIdx.z, b = bn >> 2, n = bn & 3;
    int s0 = blockIdx.y * 32, d0 = blockIdx.x * 32;
    int lx = threadIdx.x & 31, ly = threadIdx.x >> 5;
#pragma unroll
    for (int i = 0; i < 4; ++i) {
        int s = ly + i * 8;
        t[s][lx] = v[(long)(b * 1024 + s0 + s) * 2048 + n * 512 + d0 + lx];
    }
    __syncthreads();
#pragma unroll
    for (int i = 0; i < 4; ++i) {
        int d = ly + i * 8;
        vT[((long)bn * 512 + d0 + d) * 1024 + s0 + lx] = t[lx][d];
    }
}

// ---------------------------------------------------------------------------
// XCD-local persistent LSTM. 512 blocks launched; blocks register per-XCD
// (s_getreg HW_REG_XCC_ID); first XCD to 64 registrants wins; its 64 blocks
// (16 h-units each, w_hh slice in VGPRs) run the recurrence, rest exit.
// h exchange: tagged words {h<<16|step+1}; producers store via agent atomics
// (write-through shared L2/IC); consumers poll their own fragments with
// non-atomic sc0 loads (L1-bypass, shared-L2 hit, no atomic serialization).
// Sticky escalation to sc0+sc1 (IC-coherent) keeps it correct & live even if
// placement/getreg assumptions fail. Step 0 skips polling (h0 = 0).
// ---------------------------------------------------------------------------
__global__ __launch_bounds__(256, 2) void k_lstm(
    const short* __restrict__ whh, const short* __restrict__ igb,
    unsigned* __restrict__ ht,      // [2][8][1024] tagged h (no init needed)
    short* __restrict__ lstm_pad, int* __restrict__ claim)
{
    const int tid = threadIdx.x;
    __shared__ int s_rank, s_win;
    if (tid == 0) {
        int xcd = __builtin_amdgcn_s_getreg(6164) & 7;   // hwreg(XCC_ID=20,0,4)
        int rk = __hip_atomic_fetch_add(&claim[xcd], 1, __ATOMIC_RELAXED, __HIP_MEMORY_SCOPE_AGENT);
        if (rk == 63) {
            int expected = -1;
            __hip_atomic_compare_exchange_strong(&claim[8], &expected, xcd,
                __ATOMIC_RELAXED, __ATOMIC_RELAXED, __HIP_MEMORY_SCOPE_AGENT);
        }
        int w; long guard = 0;
        while ((w = __hip_atomic_load(&claim[8], __ATOMIC_RELAXED, __HIP_MEMORY_SCOPE_AGENT)) == -1) {
            __builtin_amdgcn_s_sleep(2);
            if (++guard > 50000000L) { w = -2; break; }
        }
        s_rank = (w == xcd) ? rk : 64;
        s_win = w;
    }
    __syncthreads();
    const int r = s_rank;
    if (r >= 64 || s_win < 0) return;

    const int ln = tid & 63, wv = tid >> 6;
    const int m = ln & 15;               // A-row (batch) / B n-index
    const bool act8 = (m < 8);
    const int kbase = wv * 256 + ((ln >> 4) << 3);

    // w_hh B-fragments: 4 gate-tiles x 8 k-frags (K quarter per wave)
    short8 wf[4][8];
#pragma unroll
    for (int q = 0; q < 4; ++q) {
        long row = (long)q * 1024 + r * 16 + m;
#pragma unroll
        for (int kk = 0; kk < 8; ++kk)
            wf[q][kk] = *(const short8*)&whh[row * 1024 + kbase + kk * 32];
    }

    __shared__ float part[4][16][68];
    const int gm = tid >> 4, gj = tid & 15;   // gate threads: tid<128
    float c_prev = 0.f;
    float igv[4];
    if (tid < 128) {
#pragma unroll
        for (int q = 0; q < 4; ++q)
            igv[q] = b2f(igb[((long)gm * 1024 + 0) * 4096 + q * 1024 + r * 16 + gj]);
    }

    int fastlim = 16;

    for (int step = 0; step < 1024; ++step) {
        const unsigned tag = (unsigned)step;
        float4v acc[4];
#pragma unroll
        for (int q = 0; q < 4; ++q) acc[q] = (float4v){0.f, 0.f, 0.f, 0.f};

#pragma unroll
        for (int half = 0; half < 2; ++half) {
            short8 at[4];
            if (step > 0) {
                const unsigned* ap = ht + ((step & 1) << 13) + (m << 10) + kbase + half * 128;
                uint4v w0, w1, w2, w3, w4, w5, w6, w7;
                int att = 0;
                for (;;) {
                    unsigned bad = 0;
                    if (act8) {
                        if (att >= fastlim) load8_coh(ap, w0, w1, w2, w3, w4, w5, w6, w7);
                        else                load8_fast(ap, w0, w1, w2, w3, w4, w5, w6, w7);
                        unsigned xo = (w0[0] ^ tag) | (w0[1] ^ tag) | (w0[2] ^ tag) | (w0[3] ^ tag)
                                    | (w1[0] ^ tag) | (w1[1] ^ tag) | (w1[2] ^ tag) | (w1[3] ^ tag)
                                    | (w2[0] ^ tag) | (w2[1] ^ tag) | (w2[2] ^ tag) | (w2[3] ^ tag)
                                    | (w3[0] ^ tag) | (w3[1] ^ tag) | (w3[2] ^ tag) | (w3[3] ^ tag)
                                    | (w4[0] ^ tag) | (w4[1] ^ tag) | (w4[2] ^ tag) | (w4[3] ^ tag)
                                    | (w5[0] ^ tag) | (w5[1] ^ tag) | (w5[2] ^ tag) | (w5[3] ^ tag)
                                    | (w6[0] ^ tag) | (w6[1] ^ tag) | (w6[2] ^ tag) | (w6[3] ^ tag)
                                    | (w7[0] ^ tag) | (w7[1] ^ tag) | (w7[2] ^ tag) | (w7[3] ^ tag);
                        bad = xo & 0xffffu;
                    }
                    if (__all(bad == 0u)) break;
                    if (++att > 1000000) break;       // bail: fail visibly, never hang
                    __builtin_amdgcn_s_sleep(1);
                }
                if (att >= fastlim) fastlim >>= 1;    // sticky degradation to coherent path
                if (act8) {
                    at[0] = unpack2(w0, w1); at[1] = unpack2(w2, w3);
                    at[2] = unpack2(w4, w5); at[3] = unpack2(w6, w7);
                } else {
#pragma unroll
                    for (int t = 0; t < 4; ++t) at[t] = (short8){0,0,0,0,0,0,0,0};
                }
            } else {
#pragma unroll
                for (int t = 0; t < 4; ++t) at[t] = (short8){0,0,0,0,0,0,0,0};
            }
#pragma unroll
            for (int t = 0; t < 4; ++t) {
#pragma unroll
                for (int q = 0; q < 4; ++q)
                    acc[q] = __builtin_amdgcn_mfma_f32_16x16x32_bf16(at[t], wf[q][half * 4 + t],
                                                                     acc[q], 0, 0, 0);
            }
        }

#pragma unroll
        for (int q = 0; q < 4; ++q)
#pragma unroll
            for (int rr = 0; rr < 4; ++rr)
                part[wv][(ln >> 4) * 4 + rr][q * 16 + (ln & 15)] = acc[q][rr];
        __syncthreads();

        float psum[4];
        if (tid < 128) {
#pragma unroll
            for (int q = 0; q < 4; ++q)
                psum[q] = part[0][gm][q * 16 + gj] + part[1][gm][q * 16 + gj]
                        + part[2][gm][q * 16 + gj] + part[3][gm][q * 16 + gj];
        }
        __syncthreads();

        if (tid < 128) {
            float g0 = psum[0] + igv[0];
            float g1 = psum[1] + igv[1];
            float g2 = psum[2] + igv[2];
            float g3 = psum[3] + igv[3];
            float iv = 1.f / (1.f + __expf(-g0));
            float fv = 1.f / (1.f + __expf(-g1));
            float gv = 2.f / (1.f + __expf(-2.f * g2)) - 1.f;
            float ov = 1.f / (1.f + __expf(-g3));
            float c = fv * c_prev + iv * gv;
            c_prev = c;
            float h = ov * (2.f / (1.f + __expf(-2.f * c)) - 1.f);
            short hb16 = f2b(h);
            unsigned word = ((unsigned)(unsigned short)hb16 << 16) | (unsigned)(step + 1);
            __hip_atomic_store(&ht[(((step + 1) & 1) << 13) + (gm << 10) + r * 16 + gj],
                               word, __ATOMIC_RELAXED, __HIP_MEMORY_SCOPE_AGENT);
            lstm_pad[((long)gm * 1026 + step + 1) * 1024 + r * 16 + gj] = hb16;
            if (step + 1 < 1024) {
#pragma unroll
                for (int q = 0; q < 4; ++q)
                    igv[q] = b2f(igb[((long)gm * 1024 + step + 1) * 4096 + q * 1024 + r * 16 + gj]);
            }
        }
    }
}

// ---------------------------------------------------------------------------
// conv2: a1 [8192][512] bf16 (relu'd), w [2][512][3], out a2 [8][2][1024] fp32
// ---------------------------------------------------------------------------
__global__ __launch_bounds__(256) void k_conv2(const short* __restrict__ a1,
                                               const float* __restrict__ w,
                                               const float* __restrict__ bias,
                                               float* __restrict__ a2) {
    int idx = blockIdx.x * blockDim.x + threadIdx.x;
    if (idx >= 8 * 2 * 1024) return;
    int t = idx & 1023, c = (idx >> 10) & 1, b = idx >> 11;
    float s = bias[c];
    for (int dk = 0; dk < 3; ++dk) {
        int tt = t + dk - 1;
        if (tt < 0 || tt >= 1024) continue;
        const short* arow = a1 + (long)(b * 1024 + tt) * 512;
        const float* wrow = w + c * 1536 + dk;
        for (int j = 0; j < 512; ++j) s += b2f(arow[j]) * wrow[j * 3];
    }
    a2[idx] = s;
}

// ---------------------------------------------------------------------------
// feat[b][c][h] = sum_t attw[(b*2+c)*1024+t] * lstm_pad[b][t+1][h]
// ---------------------------------------------------------------------------
__global__ __launch_bounds__(256) void k_feat(const float* __restrict__ attw,
                                              const short* __restrict__ lstm_pad,
                                              float* __restrict__ out) {
    int bc = blockIdx.x;
    int b = bc >> 1;
    int tid = threadIdx.x;
    __shared__ float aw[1024];
    for (int i = tid; i < 1024; i += 256) aw[i] = attw[bc * 1024 + i];
    __syncthreads();
    float acc[4] = {0.f, 0.f, 0.f, 0.f};
    for (int t = 0; t < 1024; ++t) {
        float a = aw[t];
        const short* hrow = lstm_pad + ((long)(b * 1026 + t + 1)) * 1024;
#pragma unroll
        for (int i = 0; i < 4; ++i) acc[i] += a * b2f(hrow[tid + (i << 8)]);
    }
#pragma unroll
    for (int i = 0; i < 4; ++i) out[bc * 1024 + tid + (i << 8)] = acc[i];
}

// ---------------------------------------------------------------------------
// Host orchestration
// ---------------------------------------------------------------------------
static void gemm_bt(hipStream_t st, const short* A, const short* B, float* Cf, short* Cb,
                    const float* bias, int M, int N, int K, int lda, int ldb, int ldc,
                    int z, int z0n, long sA0, long sA1, long sB0, long sB1, long sC0, long sC1,
                    int act, int gap) {
    dim3 grid(N / 128, M / 128, z);
    k_gemm_bt<<<grid, dim3(256), 0, st>>>(A, B, Cf, Cb, bias, M, N, K, lda, ldb, ldc,
                                          z0n, sA0, sA1, sB0, sB1, sC0, sC1, act, gap);
}

extern "C" void kernel_launch(void* const* d_in, const int* in_sizes, int n_in,
                              void* d_out, int out_size, void* d_ws, size_t ws_size,
                              hipStream_t stream) {
    if (ws_size < 199409920u) return;

    const float* x     = (const float*)d_in[0];
    const float* w_in1 = (const float*)d_in[1];
    const float* b_in1 = (const float*)d_in[2];
    const float* w_in2 = (const float*)d_in[3];
    const float* b_in2 = (const float*)d_in[4];
    const float* w_q   = (const float*)d_in[5];
    const float* b_q   = (const float*)d_in[6];
    const float* w_k   = (const float*)d_in[7];
    const float* b_k   = (const float*)d_in[8];
    const float* w_v   = (const float*)d_in[9];
    const float* b_v   = (const float*)d_in[10];
    const float* w_p   = (const float*)d_in[11];
    const float* b_p   = (const float*)d_in[12];
    const float* ln_g  = (const float*)d_in[13];
    const float* ln_b  = (const float*)d_in[14];
    const float* w_ih  = (const float*)d_in[15];
    const float* w_hh  = (const float*)d_in[16];
    const float* b_ih  = (const float*)d_in[17];
    const float* b_hh  = (const float*)d_in[18];
    const float* w_c1  = (const float*)d_in[19];
    const float* b_c1  = (const float*)d_in[20];
    const float* w_c2  = (const float*)d_in[21];
    const float* b_c2  = (const float*)d_in[22];

    char* ws = (char*)d_ws;
    // ---- static region ----
    short* w1b  = (short*)(ws + 0);
    short* w2b  = (short*)(ws + 524288);
    short* wqb  = (short*)(ws + 1048576);
    short* wkb  = (short*)(ws + 2097152);
    short* wvb  = (short*)(ws + 3145728);
    short* wpb  = (short*)(ws + 5242880);
    short* wihb = (short*)(ws + 7340032);
    short* whhb = (short*)(ws + 11534336);
    short* wc1b = (short*)(ws + 19922944);
    float* bsum = (float*)(ws + 23068672);
    unsigned* ht = (unsigned*)(ws + 23085056);   // 64 KB tagged h (self-initializing)
    int*   claim = (int*)(ws + 23150592);        // cnt[8] + winner
    float* a2   = (float*)(ws + 23150848);
    short* lpad = (short*)(ws + 23216384);
    // ---- dynamic region D0 = 40,026,368 ----
    const size_t D0 = 40026368u;
    short* xbf   = (short*)(ws + D0);
    short* h1bf  = (short*)(ws + D0 + 8388608);
    short* h2bf  = (short*)(ws + D0 + 16777216);
    short* qbf   = (short*)(ws + D0 + 25165824);
    short* kbf   = (short*)(ws + D0 + 41943040);
    short* vbf   = (short*)(ws + D0 + 58720256);
    short* vTbf  = (short*)(ws + D0 + 92274688);
    short* scb   = (short*)(ws + D0);
    short* obf   = (short*)(ws + D0 + 125829120);
    short* ybf   = (short*)(ws + D0 + 58720256);
    short* ylnbf = (short*)(ws + D0 + 67108864);
    short* igb   = (short*)(ws + D0 + 92274688);
    short* a1bf  = (short*)(ws + D0);

    hipMemsetAsync(lpad, 0, (size_t)8 * 1026 * 1024 * 2, stream);
    hipMemsetAsync(claim, 0, 32, stream);          // cnt[0..7] = 0
    hipMemsetAsync((char*)claim + 32, 0xFF, 4, stream);  // winner = -1

    k_f32_to_bf16<<<dim3(4096), dim3(256), 0, stream>>>(x, xbf, 8192 * 512);
    k_cvt_weights<<<dim3(4096), dim3(256), 0, stream>>>(w_in1, w_in2, w_q, w_k, w_v, w_p,
                                                        w_ih, w_hh, w1b);
    k_wc1_tr<<<dim3((512 * 3072 + 255) / 256), dim3(256), 0, stream>>>(w_c1, wc1b);
    k_bias_sum<<<dim3(16), dim3(256), 0, stream>>>(b_ih, b_hh, bsum, 4096);

    gemm_bt(stream, xbf, w1b, nullptr, h1bf, b_in1, 8192, 512, 512, 512, 512, 512,
            1, 1, 0, 0, 0, 0, 0, 0, 1, 0);
    gemm_bt(stream, h1bf, w2b, nullptr, h2bf, b_in2, 8192, 512, 512, 512, 512, 512,
            1, 1, 0, 0, 0, 0, 0, 0, 0, 0);
    gemm_bt(stream, h2bf, wqb, nullptr, qbf, b_q, 8192, 1024, 512, 512, 512, 1024,
            1, 1, 0, 0, 0, 0, 0, 0, 0, 0);
    gemm_bt(stream, h2bf, wkb, nullptr, kbf, b_k, 8192, 1024, 512, 512, 512, 1024,
            1, 1, 0, 0, 0, 0, 0, 0, 0, 0);
    gemm_bt(stream, h2bf, wvb, nullptr, vbf, b_v, 8192, 2048, 512, 512, 512, 2048,
            1, 1, 0, 0, 0, 0, 0, 0, 0, 0);
    k_vT<<<dim3(16, 32, 32), dim3(256), 0, stream>>>(vbf, vTbf);

    for (int bg = 0; bg < 4; ++bg) {
        const short* qb = qbf + (long)bg * 2097152;
        const short* kb = kbf + (long)bg * 2097152;
        gemm_bt(stream, qb, kb, nullptr, scb, nullptr, 1024, 1024, 256, 1024, 1024, 1024,
                8, 4, 256, 1048576, 256, 1048576, 1048576, 4194304, 0, 0);
        k_softmax_rows_bf16<<<dim3(8192), dim3(256), 0, stream>>>(scb);
        gemm_bt(stream, scb, vTbf + (long)bg * 4194304, nullptr, obf + (long)bg * 4194304, nullptr,
                1024, 512, 1024, 1024, 1024, 2048,
                8, 4, 1048576, 4194304, 524288, 2097152, 512, 2097152, 0, 0);
    }

    gemm_bt(stream, obf, wpb, nullptr, ybf, b_p, 8192, 512, 2048, 2048, 2048, 512,
            1, 1, 0, 0, 0, 0, 0, 0, 0, 0);
    k_layernorm<<<dim3(8192), dim3(256), 0, stream>>>(ybf, ln_g, ln_b, ylnbf);
    gemm_bt(stream, ylnbf, wihb, nullptr, igb, bsum, 8192, 4096, 512, 512, 512, 4096,
            1, 1, 0, 0, 0, 0, 0, 0, 0, 0);
    k_lstm<<<dim3(512), dim3(256), 0, stream>>>(whhb, igb, ht, lpad, claim);
    gemm_bt(stream, lpad, wc1b, nullptr, a1bf, b_c1, 8192, 512, 3072, 1024, 3072, 512,
            1, 1, 0, 0, 0, 0, 0, 0, 2, 1);
    k_conv2<<<dim3(64), dim3(256), 0, stream>>>(a1bf, w_c2, b_c2, a2);
    k_softmax_rows_f32<<<dim3(16), dim3(256), 0, stream>>>(a2);
    k_feat<<<dim3(16), dim3(256), 0, stream>>>(a2, lpad, (float*)d_out);
    (void)in_sizes; (void)n_in; (void)out_size; (void)ws_size;
}

// Round 7
// 6543.793 us; speedup vs baseline: 1.6909x; 1.0671x over previous
//
#include <hip/hip_runtime.h>
#include <stdint.h>

// ---------------------------------------------------------------------------
// Types / helpers
// ---------------------------------------------------------------------------
typedef short short8 __attribute__((ext_vector_type(8)));
typedef float float4v __attribute__((ext_vector_type(4)));

__device__ __forceinline__ float b2f(short s) {
    return __uint_as_float(((unsigned)(unsigned short)s) << 16);
}
__device__ __forceinline__ short f2b(float f) {
    unsigned u = __float_as_uint(f);
    unsigned r = (u + 0x7fffu + ((u >> 16) & 1u)) >> 16;
    return (short)r;
}

// ---------------------------------------------------------------------------
// fp32 -> bf16 convert (grid-stride)
// ---------------------------------------------------------------------------
__global__ void k_f32_to_bf16(const float* __restrict__ in, short* __restrict__ out, int n) {
    int i = blockIdx.x * blockDim.x + threadIdx.x;
    int stride = gridDim.x * blockDim.x;
    for (; i < n; i += stride) out[i] = f2b(in[i]);
}

// Fused converter for the 8 contiguous weight buffers
__global__ void k_cvt_weights(const float* __restrict__ s0, const float* __restrict__ s1,
                              const float* __restrict__ s2, const float* __restrict__ s3,
                              const float* __restrict__ s4, const float* __restrict__ s5,
                              const float* __restrict__ s6, const float* __restrict__ s7,
                              short* __restrict__ dst) {
    int i = blockIdx.x * blockDim.x + threadIdx.x;
    int stride = gridDim.x * blockDim.x;
    for (; i < 9961472; i += stride) {
        float v;
        if      (i <  262144) v = s0[i];
        else if (i <  524288) v = s1[i -  262144];
        else if (i < 1048576) v = s2[i -  524288];
        else if (i < 1572864) v = s3[i - 1048576];
        else if (i < 2621440) v = s4[i - 1572864];
        else if (i < 3670016) v = s5[i - 2621440];
        else if (i < 5767168) v = s6[i - 3670016];
        else                  v = s7[i - 5767168];
        dst[i] = f2b(v);
    }
}

// w_c1 [512][1024][3] -> bf16 [512][3*1024]
__global__ void k_wc1_tr(const float* __restrict__ in, short* __restrict__ out) {
    int i = blockIdx.x * blockDim.x + threadIdx.x;
    if (i >= 512 * 3072) return;
    int c = i / 3072, rr = i % 3072, dk = rr / 1024, h = rr % 1024;
    out[i] = f2b(in[(c * 1024 + h) * 3 + dk]);
}

__global__ void k_bias_sum(const float* __restrict__ a, const float* __restrict__ b,
                           float* __restrict__ o, int n) {
    int i = blockIdx.x * blockDim.x + threadIdx.x;
    if (i < n) o[i] = a[i] + b[i];
}

// ---------------------------------------------------------------------------
// Generic batched GEMM:  C[m][n] = act( sum_k A[m][k]*B[n][k] + bias[n] )
// ---------------------------------------------------------------------------
__global__ __launch_bounds__(256) void k_gemm_bt(
    const short* __restrict__ A, const short* __restrict__ B,
    float* __restrict__ Cf, short* __restrict__ Cb,
    const float* __restrict__ bias,
    int M, int N, int K, int lda, int ldb, int ldc,
    int z0n, long sA0, long sA1, long sB0, long sB1, long sC0, long sC1,
    int act, int gap)
{
    __shared__ __align__(16) short lds[2 * 128 * 32];
    const int z = blockIdx.z;
    const int z0 = z % z0n, z1 = z / z0n;
    A += z1 * sA1 + z0 * sA0;
    B += z1 * sB1 + z0 * sB0;
    const long coff = z1 * sC1 + z0 * sC0;
    const int tn0 = blockIdx.x * 128, tm0 = blockIdx.y * 128;
    const int tid = threadIdx.x, ln = tid & 63, wv = tid >> 6;
    const int wr = wv >> 1, wc = wv & 1;

    float4v acc[4][4];
#pragma unroll
    for (int i = 0; i < 4; ++i)
#pragma unroll
        for (int j = 0; j < 4; ++j) acc[i][j] = (float4v){0.f, 0.f, 0.f, 0.f};

    const int nk = K >> 5;
    for (int kt = 0; kt < nk; ++kt) {
        __syncthreads();
#pragma unroll
        for (int s = 0; s < 4; ++s) {
            int p = tid + (s << 8);
            int pp = p & 511;
            int row = pp >> 2;
            int gcol = (pp & 3) ^ ((pp >> 3) & 3);
            short8 val;
            if (p < 512) {
                long grow = (long)(tm0 + row);
                if (gap) grow += 2 * (grow >> 10);
                val = *(const short8*)&A[grow * (long)lda + kt * 32 + gcol * 8];
            } else {
                val = *(const short8*)&B[(long)(tn0 + row) * ldb + kt * 32 + gcol * 8];
            }
            ((short8*)lds)[(p < 512 ? 0 : 512) + pp] = val;
        }
        __syncthreads();

        short8 af[4], bf_[4];
        const int q = ln >> 4;
#pragma unroll
        for (int i = 0; i < 4; ++i) {
            int r = wr * 64 + i * 16 + (ln & 15);
            af[i] = ((short8*)lds)[r * 4 + (q ^ ((r >> 1) & 3))];
        }
#pragma unroll
        for (int j = 0; j < 4; ++j) {
            int r = wc * 64 + j * 16 + (ln & 15);
            bf_[j] = ((short8*)lds)[512 + r * 4 + (q ^ ((r >> 1) & 3))];
        }
#pragma unroll
        for (int i = 0; i < 4; ++i)
#pragma unroll
            for (int j = 0; j < 4; ++j)
                acc[i][j] = __builtin_amdgcn_mfma_f32_16x16x32_bf16(af[i], bf_[j], acc[i][j], 0, 0, 0);
    }

#pragma unroll
    for (int j = 0; j < 4; ++j) {
        int nglob = tn0 + wc * 64 + j * 16 + (ln & 15);
        float bv = bias ? bias[nglob] : 0.f;
#pragma unroll
        for (int i = 0; i < 4; ++i) {
#pragma unroll
            for (int r = 0; r < 4; ++r) {
                int mglob = tm0 + wr * 64 + i * 16 + (ln >> 4) * 4 + r;
                float v = acc[i][j][r] + bv;
                if (act == 1) v = (v >= 0.f) ? v : 0.25f * v;
                else if (act == 2) v = fmaxf(v, 0.f);
                long ci = coff + (long)mglob * ldc + nglob;
                if (Cf) Cf[ci] = v;
                if (Cb) Cb[ci] = f2b(v);
            }
        }
    }
}

// ---------------------------------------------------------------------------
// Row softmax over 1024, bf16 in-place
// ---------------------------------------------------------------------------
__global__ __launch_bounds__(256) void k_softmax_rows_bf16(short* __restrict__ p) {
    long row = blockIdx.x;
    short* r = p + (row << 10);
    int tid = threadIdx.x;
    float v[4];
    float mx = -3.4e38f;
#pragma unroll
    for (int i = 0; i < 4; ++i) { v[i] = b2f(r[tid + (i << 8)]); mx = fmaxf(mx, v[i]); }
#pragma unroll
    for (int d = 32; d > 0; d >>= 1) mx = fmaxf(mx, __shfl_down(mx, d));
    __shared__ float red[4], red2[4];
    if ((tid & 63) == 0) red[tid >> 6] = mx;
    __syncthreads();
    mx = fmaxf(fmaxf(red[0], red[1]), fmaxf(red[2], red[3]));
    float s = 0.f;
#pragma unroll
    for (int i = 0; i < 4; ++i) { v[i] = expf(v[i] - mx); s += v[i]; }
#pragma unroll
    for (int d = 32; d > 0; d >>= 1) s += __shfl_down(s, d);
    if ((tid & 63) == 0) red2[tid >> 6] = s;
    __syncthreads();
    s = red2[0] + red2[1] + red2[2] + red2[3];
    float inv = 1.f / s;
#pragma unroll
    for (int i = 0; i < 4; ++i) r[tid + (i << 8)] = f2b(v[i] * inv);
}

// fp32 softmax over T=1024, in place
__global__ __launch_bounds__(256) void k_softmax_rows_f32(float* __restrict__ p) {
    long row = blockIdx.x;
    float* r = p + (row << 10);
    int tid = threadIdx.x;
    float v[4];
    float mx = -3.4e38f;
#pragma unroll
    for (int i = 0; i < 4; ++i) { v[i] = r[tid + (i << 8)]; mx = fmaxf(mx, v[i]); }
#pragma unroll
    for (int d = 32; d > 0; d >>= 1) mx = fmaxf(mx, __shfl_down(mx, d));
    __shared__ float red[4], red2[4];
    if ((tid & 63) == 0) red[tid >> 6] = mx;
    __syncthreads();
    mx = fmaxf(fmaxf(red[0], red[1]), fmaxf(red[2], red[3]));
    float s = 0.f;
#pragma unroll
    for (int i = 0; i < 4; ++i) { v[i] = expf(v[i] - mx); s += v[i]; }
#pragma unroll
    for (int d = 32; d > 0; d >>= 1) s += __shfl_down(s, d);
    if ((tid & 63) == 0) red2[tid >> 6] = s;
    __syncthreads();
    s = red2[0] + red2[1] + red2[2] + red2[3];
    float inv = 1.f / s;
#pragma unroll
    for (int i = 0; i < 4; ++i) r[tid + (i << 8)] = v[i] * inv;
}

// ---------------------------------------------------------------------------
// LayerNorm over E=512 (bf16 in -> bf16 out), rows = 8192
// ---------------------------------------------------------------------------
__global__ __launch_bounds__(256) void k_layernorm(const short* __restrict__ y,
                                                   const float* __restrict__ gam,
                                                   const float* __restrict__ bet,
                                                   short* __restrict__ o) {
    const long row = blockIdx.x;
    const short* r = y + (row << 9);
    const int tid = threadIdx.x;
    float v0 = b2f(r[tid]), v1 = b2f(r[tid + 256]);
    float s = v0 + v1, ss = v0 * v0 + v1 * v1;
#pragma unroll
    for (int d = 32; d > 0; d >>= 1) { s += __shfl_down(s, d); ss += __shfl_down(ss, d); }
    __shared__ float rs_[4], rss[4];
    if ((tid & 63) == 0) { rs_[tid >> 6] = s; rss[tid >> 6] = ss; }
    __syncthreads();
    s = rs_[0] + rs_[1] + rs_[2] + rs_[3];
    ss = rss[0] + rss[1] + rss[2] + rss[3];
    float mean = s * (1.f / 512.f);
    float var = ss * (1.f / 512.f) - mean * mean;
    float rstd = rsqrtf(var + 1e-5f);
    short* out = o + (row << 9);
    out[tid]       = f2b((v0 - mean) * rstd * gam[tid]       + bet[tid]);
    out[tid + 256] = f2b((v1 - mean) * rstd * gam[tid + 256] + bet[tid + 256]);
}

// ---------------------------------------------------------------------------
// v [8192][2048] -> vT [32][512][1024] ([bn][d][s])
// ---------------------------------------------------------------------------
__global__ __launch_bounds__(256) void k_vT(const short* __restrict__ v, short* __restrict__ vT) {
    __shared__ short t[32][34];
    int bn = blockIdx.z, b = bn >> 2, n = bn & 3;
    int s0 = blockIdx.y * 32, d0 = blockIdx.x * 32;
    int lx = threadIdx.x & 31, ly = threadIdx.x >> 5;
#pragma unroll
    for (int i = 0; i < 4; ++i) {
        int s = ly + i * 8;
        t[s][lx] = v[(long)(b * 1024 + s0 + s) * 2048 + n * 512 + d0 + lx];
    }
    __syncthreads();
#pragma unroll
    for (int i = 0; i < 4; ++i) {
        int d = ly + i * 8;
        vT[((long)bn * 512 + d0 + d) * 1024 + s0 + lx] = t[lx][d];
    }
}

// ---------------------------------------------------------------------------
// Persistent LSTM — round-3 primitives (__hip_atomic_load/store, relaxed
// agent scope: plain sc0 sc1 codegen, IC-coherent), round-6 structure:
//  * all 4 waves poll the 128 flags at loop top (f >= step) — no
//    wave0-detect handoff, no trailing __syncthreads (2 syncs/step).
//  * wave0-local s_waitcnt vmcnt(0) (operand-free asm) drains h/lpad
//    stores before the flag store — replaces the block-wide drain.
// ---------------------------------------------------------------------------
__global__ __launch_bounds__(256) void k_lstm(
    const short* __restrict__ whh, const short* __restrict__ igb,
    short* __restrict__ hA, short* __restrict__ hB,
    short* __restrict__ lstm_pad, int* __restrict__ arr)
{
    const int g = blockIdx.x;            // 0..127
    const int tid = threadIdx.x;
    const int ln = tid & 63, wv = tid >> 6;
    const int kbase = wv * 256 + ((ln >> 4) << 3);
    const int arow = ln & 15;            // rows 8..15 stay zero (memset, never written)

    // preload w_hh fragments: B-frag lane ln holds W[n][k], n = nt*16+(ln&15)
    short8 wf[2][8];
#pragma unroll
    for (int nt = 0; nt < 2; ++nt) {
        int n = nt * 16 + (ln & 15);
        int q = n >> 3, r = n & 7;
        long row = (long)q * 1024 + g * 8 + r;
#pragma unroll
        for (int kk = 0; kk < 8; ++kk)
            wf[nt][kk] = *(const short8*)&whh[row * 1024 + kbase + kk * 32];
    }

    __shared__ float part[4][16][33];
    const int gm = tid >> 3, gu = tid & 7;   // gate lanes = wave 0 (tid<64)
    float c_prev = 0.f;
    float igv[4];
    if (tid < 64) {
#pragma unroll
        for (int q = 0; q < 4; ++q)
            igv[q] = b2f(igb[((long)gm * 1024 + 0) * 4096 + q * 1024 + g * 8 + gu]);
    }

    for (int step = 0; step < 1024; ++step) {
        // ---- barrier detect: every wave polls all 128 flags (>= step) ----
        if (step > 0) {
            long att = 0;
            for (;;) {
                int f0 = __hip_atomic_load(&arr[ln],      __ATOMIC_RELAXED, __HIP_MEMORY_SCOPE_AGENT);
                int f1 = __hip_atomic_load(&arr[ln + 64], __ATOMIC_RELAXED, __HIP_MEMORY_SCOPE_AGENT);
                if (__all(f0 >= step && f1 >= step)) break;
                if (++att > 20000000L) break;     // never hang
                __builtin_amdgcn_s_sleep(1);
            }
        }

        // ---- h fragment load (relaxed agent atomics = plain sc0 sc1 loads) ----
        const short* hp = (step & 1) ? hB : hA;
        short8 af[8];
        {
            const unsigned long long* hq =
                (const unsigned long long*)(hp + arow * 1024 + kbase);
#pragma unroll
            for (int kk = 0; kk < 8; ++kk) {
                union { unsigned long long u[2]; short8 s; } cv;
                cv.u[0] = __hip_atomic_load(hq + kk * 8,     __ATOMIC_RELAXED, __HIP_MEMORY_SCOPE_AGENT);
                cv.u[1] = __hip_atomic_load(hq + kk * 8 + 1, __ATOMIC_RELAXED, __HIP_MEMORY_SCOPE_AGENT);
                af[kk] = cv.s;
            }
        }

        float4v acc0 = (float4v){0.f, 0.f, 0.f, 0.f};
        float4v acc1 = (float4v){0.f, 0.f, 0.f, 0.f};
#pragma unroll
        for (int kk = 0; kk < 8; ++kk) {
            acc0 = __builtin_amdgcn_mfma_f32_16x16x32_bf16(af[kk], wf[0][kk], acc0, 0, 0, 0);
            acc1 = __builtin_amdgcn_mfma_f32_16x16x32_bf16(af[kk], wf[1][kk], acc1, 0, 0, 0);
        }

        __syncthreads();   // wave0 has finished reading prev-step part
#pragma unroll
        for (int rr = 0; rr < 4; ++rr) {
            part[wv][(ln >> 4) * 4 + rr][ln & 15]        = acc0[rr];
            part[wv][(ln >> 4) * 4 + rr][16 + (ln & 15)] = acc1[rr];
        }
        __syncthreads();

        if (tid < 64) {
            float psum[4];
#pragma unroll
            for (int q = 0; q < 4; ++q) {
                int nn = q * 8 + gu;
                psum[q] = part[0][gm][nn] + part[1][gm][nn] + part[2][gm][nn] + part[3][gm][nn];
            }
            float g0 = psum[0] + igv[0];
            float g1 = psum[1] + igv[1];
            float g2 = psum[2] + igv[2];
            float g3 = psum[3] + igv[3];
            float iv = 1.f / (1.f + __expf(-g0));
            float fv = 1.f / (1.f + __expf(-g1));
            float gv = 2.f / (1.f + __expf(-2.f * g2)) - 1.f;
            float ov = 1.f / (1.f + __expf(-g3));
            float c = fv * c_prev + iv * gv;
            c_prev = c;
            float h = ov * (2.f / (1.f + __expf(-2.f * c)) - 1.f);
            short hb16 = f2b(h);
            short* hn = (step & 1) ? hA : hB;
            __hip_atomic_store(&hn[gm * 1024 + g * 8 + gu], hb16,
                               __ATOMIC_RELAXED, __HIP_MEMORY_SCOPE_AGENT);
            lstm_pad[((long)gm * 1026 + step + 1) * 1024 + g * 8 + gu] = hb16;
            // wave0-local drain: h stores acked at the IC before the flag goes up
            asm volatile("s_waitcnt vmcnt(0)" ::: "memory");
            if (tid == 0)
                __hip_atomic_store(&arr[g], step + 1,
                                   __ATOMIC_RELAXED, __HIP_MEMORY_SCOPE_AGENT);
            if (step + 1 < 1024) {
#pragma unroll
                for (int q = 0; q < 4; ++q)
                    igv[q] = b2f(igb[((long)gm * 1024 + step + 1) * 4096 + q * 1024 + g * 8 + gu]);
            }
        }
        // no trailing sync: waves are held by the flag poll at loop top
    }
}

// ---------------------------------------------------------------------------
// conv2: a1 [8192][512] bf16 (relu'd), w [2][512][3] staged in LDS,
// short8-vectorized A loads. grid 64: blk = b*8 + c*4 + quarter.
// ---------------------------------------------------------------------------
__global__ __launch_bounds__(256) void k_conv2(const short* __restrict__ a1,
                                               const float* __restrict__ w,
                                               const float* __restrict__ bias,
                                               float* __restrict__ a2) {
    __shared__ float wl[1536];
    int blk = blockIdx.x;
    int b = blk >> 3, c = (blk >> 2) & 1, t0 = (blk & 3) * 256;
    int tid = threadIdx.x;
    for (int i = tid; i < 1536; i += 256) wl[i] = w[c * 1536 + i];
    __syncthreads();
    int t = t0 + tid;
    float s = bias[c];
    for (int dk = 0; dk < 3; ++dk) {
        int tt = t + dk - 1;
        if (tt < 0 || tt >= 1024) continue;
        const short8* arow = (const short8*)(a1 + (long)(b * 1024 + tt) * 512);
        for (int j = 0; j < 64; ++j) {
            short8 v = arow[j];
#pragma unroll
            for (int u = 0; u < 8; ++u)
                s += b2f(v[u]) * wl[(j * 8 + u) * 3 + dk];
        }
    }
    a2[(b * 2 + c) * 1024 + t] = s;
}

// ---------------------------------------------------------------------------
// feat[b][c][h] = sum_t attw[(b*2+c)*1024+t] * lstm_pad[b][t+1][h]
// grid 64: blk = bc*4 + h-quarter.
// ---------------------------------------------------------------------------
__global__ __launch_bounds__(256) void k_feat(const float* __restrict__ attw,
                                              const short* __restrict__ lstm_pad,
                                              float* __restrict__ out) {
    int blk = blockIdx.x;
    int bc = blk >> 2, qh = blk & 3;
    int b = bc >> 1;
    int tid = threadIdx.x;
    int h = qh * 256 + tid;
    __shared__ float aw[1024];
    for (int i = tid; i < 1024; i += 256) aw[i] = attw[bc * 1024 + i];
    __syncthreads();
    float acc = 0.f;
#pragma unroll 4
    for (int t = 0; t < 1024; ++t)
        acc += aw[t] * b2f(lstm_pad[((long)(b * 1026 + t + 1)) * 1024 + h]);
    out[bc * 1024 + h] = acc;
}

// ---------------------------------------------------------------------------
// Host orchestration
// ---------------------------------------------------------------------------
static void gemm_bt(hipStream_t st, const short* A, const short* B, float* Cf, short* Cb,
                    const float* bias, int M, int N, int K, int lda, int ldb, int ldc,
                    int z, int z0n, long sA0, long sA1, long sB0, long sB1, long sC0, long sC1,
                    int act, int gap) {
    dim3 grid(N / 128, M / 128, z);
    k_gemm_bt<<<grid, dim3(256), 0, st>>>(A, B, Cf, Cb, bias, M, N, K, lda, ldb, ldc,
                                          z0n, sA0, sA1, sB0, sB1, sC0, sC1, act, gap);
}

extern "C" void kernel_launch(void* const* d_in, const int* in_sizes, int n_in,
                              void* d_out, int out_size, void* d_ws, size_t ws_size,
                              hipStream_t stream) {
    if (ws_size < 199409920u) return;

    const float* x     = (const float*)d_in[0];
    const float* w_in1 = (const float*)d_in[1];
    const float* b_in1 = (const float*)d_in[2];
    const float* w_in2 = (const float*)d_in[3];
    const float* b_in2 = (const float*)d_in[4];
    const float* w_q   = (const float*)d_in[5];
    const float* b_q   = (const float*)d_in[6];
    const float* w_k   = (const float*)d_in[7];
    const float* b_k   = (const float*)d_in[8];
    const float* w_v   = (const float*)d_in[9];
    const float* b_v   = (const float*)d_in[10];
    const float* w_p   = (const float*)d_in[11];
    const float* b_p   = (const float*)d_in[12];
    const float* ln_g  = (const float*)d_in[13];
    const float* ln_b  = (const float*)d_in[14];
    const float* w_ih  = (const float*)d_in[15];
    const float* w_hh  = (const float*)d_in[16];
    const float* b_ih  = (const float*)d_in[17];
    const float* b_hh  = (const float*)d_in[18];
    const float* w_c1  = (const float*)d_in[19];
    const float* b_c1  = (const float*)d_in[20];
    const float* w_c2  = (const float*)d_in[21];
    const float* b_c2  = (const float*)d_in[22];

    char* ws = (char*)d_ws;
    // ---- static region ----
    short* w1b  = (short*)(ws + 0);
    short* w2b  = (short*)(ws + 524288);
    short* wqb  = (short*)(ws + 1048576);
    short* wkb  = (short*)(ws + 2097152);
    short* wvb  = (short*)(ws + 3145728);
    short* wpb  = (short*)(ws + 5242880);
    short* wihb = (short*)(ws + 7340032);
    short* whhb = (short*)(ws + 11534336);
    short* wc1b = (short*)(ws + 19922944);
    float* bsum = (float*)(ws + 23068672);
    short* hs0  = (short*)(ws + 23085056);     // 32 KB
    short* hs1  = (short*)(ws + 23117824);     // 32 KB
    int*   arr  = (int*)  (ws + 23150592);     // 512 B
    float* a2   = (float*)(ws + 23150848);
    short* lpad = (short*)(ws + 23216384);
    // ---- dynamic region D0 = 40,026,368 ----
    const size_t D0 = 40026368u;
    short* xbf   = (short*)(ws + D0);
    short* h1bf  = (short*)(ws + D0 + 8388608);
    short* h2bf  = (short*)(ws + D0 + 16777216);
    short* qbf   = (short*)(ws + D0 + 25165824);
    short* kbf   = (short*)(ws + D0 + 41943040);
    short* vbf   = (short*)(ws + D0 + 58720256);
    short* vTbf  = (short*)(ws + D0 + 92274688);
    short* scb   = (short*)(ws + D0);
    short* obf   = (short*)(ws + D0 + 125829120);
    short* ybf   = (short*)(ws + D0 + 58720256);
    short* ylnbf = (short*)(ws + D0 + 67108864);
    short* igb   = (short*)(ws + D0 + 92274688);
    short* a1bf  = (short*)(ws + D0);

    hipMemsetAsync(lpad, 0, (size_t)8 * 1026 * 1024 * 2, stream);
    hipMemsetAsync(hs0, 0, 32768, stream);
    hipMemsetAsync(hs1, 0, 32768, stream);
    hipMemsetAsync(arr, 0, 512, stream);

    k_f32_to_bf16<<<dim3(4096), dim3(256), 0, stream>>>(x, xbf, 8192 * 512);
    k_cvt_weights<<<dim3(4096), dim3(256), 0, stream>>>(w_in1, w_in2, w_q, w_k, w_v, w_p,
                                                        w_ih, w_hh, w1b);
    k_wc1_tr<<<dim3((512 * 3072 + 255) / 256), dim3(256), 0, stream>>>(w_c1, wc1b);
    k_bias_sum<<<dim3(16), dim3(256), 0, stream>>>(b_ih, b_hh, bsum, 4096);

    gemm_bt(stream, xbf, w1b, nullptr, h1bf, b_in1, 8192, 512, 512, 512, 512, 512,
            1, 1, 0, 0, 0, 0, 0, 0, 1, 0);
    gemm_bt(stream, h1bf, w2b, nullptr, h2bf, b_in2, 8192, 512, 512, 512, 512, 512,
            1, 1, 0, 0, 0, 0, 0, 0, 0, 0);
    gemm_bt(stream, h2bf, wqb, nullptr, qbf, b_q, 8192, 1024, 512, 512, 512, 1024,
            1, 1, 0, 0, 0, 0, 0, 0, 0, 0);
    gemm_bt(stream, h2bf, wkb, nullptr, kbf, b_k, 8192, 1024, 512, 512, 512, 1024,
            1, 1, 0, 0, 0, 0, 0, 0, 0, 0);
    gemm_bt(stream, h2bf, wvb, nullptr, vbf, b_v, 8192, 2048, 512, 512, 512, 2048,
            1, 1, 0, 0, 0, 0, 0, 0, 0, 0);
    k_vT<<<dim3(16, 32, 32), dim3(256), 0, stream>>>(vbf, vTbf);

    for (int bg = 0; bg < 4; ++bg) {
        const short* qb = qbf + (long)bg * 2097152;
        const short* kb = kbf + (long)bg * 2097152;
        gemm_bt(stream, qb, kb, nullptr, scb, nullptr, 1024, 1024, 256, 1024, 1024, 1024,
                8, 4, 256, 1048576, 256, 1048576, 1048576, 4194304, 0, 0);
        k_softmax_rows_bf16<<<dim3(8192), dim3(256), 0, stream>>>(scb);
        gemm_bt(stream, scb, vTbf + (long)bg * 4194304, nullptr, obf + (long)bg * 4194304, nullptr,
                1024, 512, 1024, 1024, 1024, 2048,
                8, 4, 1048576, 4194304, 524288, 2097152, 512, 2097152, 0, 0);
    }

    gemm_bt(stream, obf, wpb, nullptr, ybf, b_p, 8192, 512, 2048, 2048, 2048, 512,
            1, 1, 0, 0, 0, 0, 0, 0, 0, 0);
    k_layernorm<<<dim3(8192), dim3(256), 0, stream>>>(ybf, ln_g, ln_b, ylnbf);
    gemm_bt(stream, ylnbf, wihb, nullptr, igb, bsum, 8192, 4096, 512, 512, 512, 4096,
            1, 1, 0, 0, 0, 0, 0, 0, 0, 0);
    k_lstm<<<dim3(128), dim3(256), 0, stream>>>(whhb, igb, hs0, hs1, lpad, arr);
    gemm_bt(stream, lpad, wc1b, nullptr, a1bf, b_c1, 8192, 512, 3072, 1024, 3072, 512,
            1, 1, 0, 0, 0, 0, 0, 0, 2, 1);
    k_conv2<<<dim3(64), dim3(256), 0, stream>>>(a1bf, w_c2, b_c2, a2);
    k_softmax_rows_f32<<<dim3(16), dim3(256), 0, stream>>>(a2);
    k_feat<<<dim3(64), dim3(256), 0, stream>>>(a2, lpad, (float*)d_out);
    (void)in_sizes; (void)n_in; (void)out_size; (void)ws_size;
}

// Round 8
// 4183.018 us; speedup vs baseline: 2.6452x; 1.5644x over previous
//
#include <hip/hip_runtime.h>
#include <stdint.h>

// ---------------------------------------------------------------------------
// Types / helpers
// ---------------------------------------------------------------------------
typedef short short8 __attribute__((ext_vector_type(8)));
typedef float float4v __attribute__((ext_vector_type(4)));

__device__ __forceinline__ float b2f(short s) {
    return __uint_as_float(((unsigned)(unsigned short)s) << 16);
}
__device__ __forceinline__ short f2b(float f) {
    unsigned u = __float_as_uint(f);
    unsigned r = (u + 0x7fffu + ((u >> 16) & 1u)) >> 16;
    return (short)r;
}

// ---------------------------------------------------------------------------
// fp32 -> bf16 convert (grid-stride)
// ---------------------------------------------------------------------------
__global__ void k_f32_to_bf16(const float* __restrict__ in, short* __restrict__ out, int n) {
    int i = blockIdx.x * blockDim.x + threadIdx.x;
    int stride = gridDim.x * blockDim.x;
    for (; i < n; i += stride) out[i] = f2b(in[i]);
}

// Fused converter for the 8 contiguous weight buffers
__global__ void k_cvt_weights(const float* __restrict__ s0, const float* __restrict__ s1,
                              const float* __restrict__ s2, const float* __restrict__ s3,
                              const float* __restrict__ s4, const float* __restrict__ s5,
                              const float* __restrict__ s6, const float* __restrict__ s7,
                              short* __restrict__ dst) {
    int i = blockIdx.x * blockDim.x + threadIdx.x;
    int stride = gridDim.x * blockDim.x;
    for (; i < 9961472; i += stride) {
        float v;
        if      (i <  262144) v = s0[i];
        else if (i <  524288) v = s1[i -  262144];
        else if (i < 1048576) v = s2[i -  524288];
        else if (i < 1572864) v = s3[i - 1048576];
        else if (i < 2621440) v = s4[i - 1572864];
        else if (i < 3670016) v = s5[i - 2621440];
        else if (i < 5767168) v = s6[i - 3670016];
        else                  v = s7[i - 5767168];
        dst[i] = f2b(v);
    }
}

// w_c1 [512][1024][3] -> bf16 [512][3*1024]
__global__ void k_wc1_tr(const float* __restrict__ in, short* __restrict__ out) {
    int i = blockIdx.x * blockDim.x + threadIdx.x;
    if (i >= 512 * 3072) return;
    int c = i / 3072, rr = i % 3072, dk = rr / 1024, h = rr % 1024;
    out[i] = f2b(in[(c * 1024 + h) * 3 + dk]);
}

__global__ void k_bias_sum(const float* __restrict__ a, const float* __restrict__ b,
                           float* __restrict__ o, int n) {
    int i = blockIdx.x * blockDim.x + threadIdx.x;
    if (i < n) o[i] = a[i] + b[i];
}

// ---------------------------------------------------------------------------
// Generic batched GEMM:  C[m][n] = act( sum_k A[m][k]*B[n][k] + bias[n] )
// ---------------------------------------------------------------------------
__global__ __launch_bounds__(256) void k_gemm_bt(
    const short* __restrict__ A, const short* __restrict__ B,
    float* __restrict__ Cf, short* __restrict__ Cb,
    const float* __restrict__ bias,
    int M, int N, int K, int lda, int ldb, int ldc,
    int z0n, long sA0, long sA1, long sB0, long sB1, long sC0, long sC1,
    int act, int gap)
{
    __shared__ __align__(16) short lds[2 * 128 * 32];
    const int z = blockIdx.z;
    const int z0 = z % z0n, z1 = z / z0n;
    A += z1 * sA1 + z0 * sA0;
    B += z1 * sB1 + z0 * sB0;
    const long coff = z1 * sC1 + z0 * sC0;
    const int tn0 = blockIdx.x * 128, tm0 = blockIdx.y * 128;
    const int tid = threadIdx.x, ln = tid & 63, wv = tid >> 6;
    const int wr = wv >> 1, wc = wv & 1;

    float4v acc[4][4];
#pragma unroll
    for (int i = 0; i < 4; ++i)
#pragma unroll
        for (int j = 0; j < 4; ++j) acc[i][j] = (float4v){0.f, 0.f, 0.f, 0.f};

    const int nk = K >> 5;
    for (int kt = 0; kt < nk; ++kt) {
        __syncthreads();
#pragma unroll
        for (int s = 0; s < 4; ++s) {
            int p = tid + (s << 8);
            int pp = p & 511;
            int row = pp >> 2;
            int gcol = (pp & 3) ^ ((pp >> 3) & 3);
            short8 val;
            if (p < 512) {
                long grow = (long)(tm0 + row);
                if (gap) grow += 2 * (grow >> 10);
                val = *(const short8*)&A[grow * (long)lda + kt * 32 + gcol * 8];
            } else {
                val = *(const short8*)&B[(long)(tn0 + row) * ldb + kt * 32 + gcol * 8];
            }
            ((short8*)lds)[(p < 512 ? 0 : 512) + pp] = val;
        }
        __syncthreads();

        short8 af[4], bf_[4];
        const int q = ln >> 4;
#pragma unroll
        for (int i = 0; i < 4; ++i) {
            int r = wr * 64 + i * 16 + (ln & 15);
            af[i] = ((short8*)lds)[r * 4 + (q ^ ((r >> 1) & 3))];
        }
#pragma unroll
        for (int j = 0; j < 4; ++j) {
            int r = wc * 64 + j * 16 + (ln & 15);
            bf_[j] = ((short8*)lds)[512 + r * 4 + (q ^ ((r >> 1) & 3))];
        }
#pragma unroll
        for (int i = 0; i < 4; ++i)
#pragma unroll
            for (int j = 0; j < 4; ++j)
                acc[i][j] = __builtin_amdgcn_mfma_f32_16x16x32_bf16(af[i], bf_[j], acc[i][j], 0, 0, 0);
    }

#pragma unroll
    for (int j = 0; j < 4; ++j) {
        int nglob = tn0 + wc * 64 + j * 16 + (ln & 15);
        float bv = bias ? bias[nglob] : 0.f;
#pragma unroll
        for (int i = 0; i < 4; ++i) {
#pragma unroll
            for (int r = 0; r < 4; ++r) {
                int mglob = tm0 + wr * 64 + i * 16 + (ln >> 4) * 4 + r;
                float v = acc[i][j][r] + bv;
                if (act == 1) v = (v >= 0.f) ? v : 0.25f * v;
                else if (act == 2) v = fmaxf(v, 0.f);
                long ci = coff + (long)mglob * ldc + nglob;
                if (Cf) Cf[ci] = v;
                if (Cb) Cb[ci] = f2b(v);
            }
        }
    }
}

// ---------------------------------------------------------------------------
// Row softmax over 1024, bf16 in-place
// ---------------------------------------------------------------------------
__global__ __launch_bounds__(256) void k_softmax_rows_bf16(short* __restrict__ p) {
    long row = blockIdx.x;
    short* r = p + (row << 10);
    int tid = threadIdx.x;
    float v[4];
    float mx = -3.4e38f;
#pragma unroll
    for (int i = 0; i < 4; ++i) { v[i] = b2f(r[tid + (i << 8)]); mx = fmaxf(mx, v[i]); }
#pragma unroll
    for (int d = 32; d > 0; d >>= 1) mx = fmaxf(mx, __shfl_down(mx, d));
    __shared__ float red[4], red2[4];
    if ((tid & 63) == 0) red[tid >> 6] = mx;
    __syncthreads();
    mx = fmaxf(fmaxf(red[0], red[1]), fmaxf(red[2], red[3]));
    float s = 0.f;
#pragma unroll
    for (int i = 0; i < 4; ++i) { v[i] = expf(v[i] - mx); s += v[i]; }
#pragma unroll
    for (int d = 32; d > 0; d >>= 1) s += __shfl_down(s, d);
    if ((tid & 63) == 0) red2[tid >> 6] = s;
    __syncthreads();
    s = red2[0] + red2[1] + red2[2] + red2[3];
    float inv = 1.f / s;
#pragma unroll
    for (int i = 0; i < 4; ++i) r[tid + (i << 8)] = f2b(v[i] * inv);
}

// fp32 softmax over T=1024, in place
__global__ __launch_bounds__(256) void k_softmax_rows_f32(float* __restrict__ p) {
    long row = blockIdx.x;
    float* r = p + (row << 10);
    int tid = threadIdx.x;
    float v[4];
    float mx = -3.4e38f;
#pragma unroll
    for (int i = 0; i < 4; ++i) { v[i] = r[tid + (i << 8)]; mx = fmaxf(mx, v[i]); }
#pragma unroll
    for (int d = 32; d > 0; d >>= 1) mx = fmaxf(mx, __shfl_down(mx, d));
    __shared__ float red[4], red2[4];
    if ((tid & 63) == 0) red[tid >> 6] = mx;
    __syncthreads();
    mx = fmaxf(fmaxf(red[0], red[1]), fmaxf(red[2], red[3]));
    float s = 0.f;
#pragma unroll
    for (int i = 0; i < 4; ++i) { v[i] = expf(v[i] - mx); s += v[i]; }
#pragma unroll
    for (int d = 32; d > 0; d >>= 1) s += __shfl_down(s, d);
    if ((tid & 63) == 0) red2[tid >> 6] = s;
    __syncthreads();
    s = red2[0] + red2[1] + red2[2] + red2[3];
    float inv = 1.f / s;
#pragma unroll
    for (int i = 0; i < 4; ++i) r[tid + (i << 8)] = v[i] * inv;
}

// ---------------------------------------------------------------------------
// LayerNorm over E=512 (bf16 in -> bf16 out), rows = 8192
// ---------------------------------------------------------------------------
__global__ __launch_bounds__(256) void k_layernorm(const short* __restrict__ y,
                                                   const float* __restrict__ gam,
                                                   const float* __restrict__ bet,
                                                   short* __restrict__ o) {
    const long row = blockIdx.x;
    const short* r = y + (row << 9);
    const int tid = threadIdx.x;
    float v0 = b2f(r[tid]), v1 = b2f(r[tid + 256]);
    float s = v0 + v1, ss = v0 * v0 + v1 * v1;
#pragma unroll
    for (int d = 32; d > 0; d >>= 1) { s += __shfl_down(s, d); ss += __shfl_down(ss, d); }
    __shared__ float rs_[4], rss[4];
    if ((tid & 63) == 0) { rs_[tid >> 6] = s; rss[tid >> 6] = ss; }
    __syncthreads();
    s = rs_[0] + rs_[1] + rs_[2] + rs_[3];
    ss = rss[0] + rss[1] + rss[2] + rss[3];
    float mean = s * (1.f / 512.f);
    float var = ss * (1.f / 512.f) - mean * mean;
    float rstd = rsqrtf(var + 1e-5f);
    short* out = o + (row << 9);
    out[tid]       = f2b((v0 - mean) * rstd * gam[tid]       + bet[tid]);
    out[tid + 256] = f2b((v1 - mean) * rstd * gam[tid + 256] + bet[tid + 256]);
}

// ---------------------------------------------------------------------------
// v [8192][2048] -> vT [32][512][1024] ([bn][d][s])
// ---------------------------------------------------------------------------
__global__ __launch_bounds__(256) void k_vT(const short* __restrict__ v, short* __restrict__ vT) {
    __shared__ short t[32][34];
    int bn = blockIdx.z, b = bn >> 2, n = bn & 3;
    int s0 = blockIdx.y * 32, d0 = blockIdx.x * 32;
    int lx = threadIdx.x & 31, ly = threadIdx.x >> 5;
#pragma unroll
    for (int i = 0; i < 4; ++i) {
        int s = ly + i * 8;
        t[s][lx] = v[(long)(b * 1024 + s0 + s) * 2048 + n * 512 + d0 + lx];
    }
    __syncthreads();
#pragma unroll
    for (int i = 0; i < 4; ++i) {
        int d = ly + i * 8;
        vT[((long)bn * 512 + d0 + d) * 1024 + s0 + lx] = t[lx][d];
    }
}

// ---------------------------------------------------------------------------
// Persistent LSTM — round-3 protocol verbatim (wave0-only poll, 3 syncs,
// relaxed agent atomics), but 64 blocks (16 h-units each):
//   * 64 flags (one load per wave0 lane), half the pollers, half the
//     flag stores per step, half the skew pool vs round 3's 128 blocks.
//   * per wave: 4 gate-tiles x 8 k-frags = 32 MFMAs (~+80 cyc, noise).
// ---------------------------------------------------------------------------
__global__ __launch_bounds__(256) void k_lstm(
    const short* __restrict__ whh, const short* __restrict__ igb,
    short* __restrict__ hA, short* __restrict__ hB,
    short* __restrict__ lstm_pad, int* __restrict__ arr)
{
    const int g = blockIdx.x;            // 0..63, owns units g*16..g*16+15
    const int tid = threadIdx.x;
    const int ln = tid & 63, wv = tid >> 6;
    const int kbase = wv * 256 + ((ln >> 4) << 3);
    const int arow = ln & 15;            // batch rows; 8..15 stay zero

    // wf[q][kk]: B-frag for gate q's 16 rows (units), this wave's K-quarter
    short8 wf[4][8];
#pragma unroll
    for (int q = 0; q < 4; ++q) {
        long row = (long)q * 1024 + g * 16 + (ln & 15);
#pragma unroll
        for (int kk = 0; kk < 8; ++kk)
            wf[q][kk] = *(const short8*)&whh[row * 1024 + kbase + kk * 32];
    }

    __shared__ float part[4][16][68];
    const int gm = tid >> 4, gu = tid & 15;   // gate threads tid<128: batch, unit
    float c_prev = 0.f;
    float igv[4];
    if (tid < 128) {
#pragma unroll
        for (int q = 0; q < 4; ++q)
            igv[q] = b2f(igb[((long)gm * 1024 + 0) * 4096 + q * 1024 + g * 16 + gu]);
    }

    for (int step = 0; step < 1024; ++step) {
        // ---- h fragment load (relaxed agent atomics = plain sc0 sc1) ----
        const short* hp = (step & 1) ? hB : hA;
        short8 af[8];
        if (arow < 8) {
            const unsigned long long* hq =
                (const unsigned long long*)(hp + arow * 1024 + kbase);
#pragma unroll
            for (int kk = 0; kk < 8; ++kk) {
                union { unsigned long long u[2]; short8 s; } cv;
                cv.u[0] = __hip_atomic_load(hq + kk * 8,     __ATOMIC_RELAXED, __HIP_MEMORY_SCOPE_AGENT);
                cv.u[1] = __hip_atomic_load(hq + kk * 8 + 1, __ATOMIC_RELAXED, __HIP_MEMORY_SCOPE_AGENT);
                af[kk] = cv.s;
            }
        } else {
#pragma unroll
            for (int kk = 0; kk < 8; ++kk) af[kk] = (short8){0, 0, 0, 0, 0, 0, 0, 0};
        }

        float4v acc[4];
#pragma unroll
        for (int q = 0; q < 4; ++q) acc[q] = (float4v){0.f, 0.f, 0.f, 0.f};
#pragma unroll
        for (int kk = 0; kk < 8; ++kk)
#pragma unroll
            for (int q = 0; q < 4; ++q)
                acc[q] = __builtin_amdgcn_mfma_f32_16x16x32_bf16(af[kk], wf[q][kk], acc[q], 0, 0, 0);

        // part write protected by previous iteration's trailing sync
#pragma unroll
        for (int q = 0; q < 4; ++q)
#pragma unroll
            for (int rr = 0; rr < 4; ++rr)
                part[wv][(ln >> 4) * 4 + rr][q * 16 + (ln & 15)] = acc[q][rr];
        __syncthreads();

        if (tid < 128) {
            float psum[4];
#pragma unroll
            for (int q = 0; q < 4; ++q)
                psum[q] = part[0][gm][q * 16 + gu] + part[1][gm][q * 16 + gu]
                        + part[2][gm][q * 16 + gu] + part[3][gm][q * 16 + gu];
            float g0 = psum[0] + igv[0];
            float g1 = psum[1] + igv[1];
            float g2 = psum[2] + igv[2];
            float g3 = psum[3] + igv[3];
            float iv = 1.f / (1.f + __expf(-g0));
            float fv = 1.f / (1.f + __expf(-g1));
            float gv = 2.f / (1.f + __expf(-2.f * g2)) - 1.f;
            float ov = 1.f / (1.f + __expf(-g3));
            float c = fv * c_prev + iv * gv;
            c_prev = c;
            float h = ov * (2.f / (1.f + __expf(-2.f * c)) - 1.f);
            short hb16 = f2b(h);
            short* hn = (step & 1) ? hA : hB;
            __hip_atomic_store(&hn[gm * 1024 + g * 16 + gu], hb16,
                               __ATOMIC_RELAXED, __HIP_MEMORY_SCOPE_AGENT);
            lstm_pad[((long)gm * 1026 + step + 1) * 1024 + g * 16 + gu] = hb16;
        }

        __syncthreads();   // per-wave vmcnt drain: h stores acked before flag
        if (tid == 0)
            __hip_atomic_store(&arr[g], step + 1, __ATOMIC_RELAXED, __HIP_MEMORY_SCOPE_AGENT);
        // prefetch next step's ig during the poll wait
        if (tid < 128 && step + 1 < 1024) {
#pragma unroll
            for (int q = 0; q < 4; ++q)
                igv[q] = b2f(igb[((long)gm * 1024 + step + 1) * 4096 + q * 1024 + g * 16 + gu]);
        }
        if (wv == 0) {
            const int target = step + 1;
            long att = 0;
            while (true) {
                int f0 = __hip_atomic_load(&arr[ln], __ATOMIC_RELAXED, __HIP_MEMORY_SCOPE_AGENT);
                if (__all(f0 >= target)) break;
                if (++att > 20000000L) break;   // never hang
                __builtin_amdgcn_s_sleep(1);
            }
        }
        __syncthreads();
    }
}

// ---------------------------------------------------------------------------
// conv2: a1 [8192][512] bf16 (relu'd), w [2][512][3] staged in LDS,
// short8-vectorized A loads. grid 64: blk = b*8 + c*4 + quarter.
// ---------------------------------------------------------------------------
__global__ __launch_bounds__(256) void k_conv2(const short* __restrict__ a1,
                                               const float* __restrict__ w,
                                               const float* __restrict__ bias,
                                               float* __restrict__ a2) {
    __shared__ float wl[1536];
    int blk = blockIdx.x;
    int b = blk >> 3, c = (blk >> 2) & 1, t0 = (blk & 3) * 256;
    int tid = threadIdx.x;
    for (int i = tid; i < 1536; i += 256) wl[i] = w[c * 1536 + i];
    __syncthreads();
    int t = t0 + tid;
    float s = bias[c];
    for (int dk = 0; dk < 3; ++dk) {
        int tt = t + dk - 1;
        if (tt < 0 || tt >= 1024) continue;
        const short8* arow = (const short8*)(a1 + (long)(b * 1024 + tt) * 512);
        for (int j = 0; j < 64; ++j) {
            short8 v = arow[j];
#pragma unroll
            for (int u = 0; u < 8; ++u)
                s += b2f(v[u]) * wl[(j * 8 + u) * 3 + dk];
        }
    }
    a2[(b * 2 + c) * 1024 + t] = s;
}

// ---------------------------------------------------------------------------
// feat[b][c][h] = sum_t attw[(b*2+c)*1024+t] * lstm_pad[b][t+1][h]
// grid 64: blk = bc*4 + h-quarter.
// ---------------------------------------------------------------------------
__global__ __launch_bounds__(256) void k_feat(const float* __restrict__ attw,
                                              const short* __restrict__ lstm_pad,
                                              float* __restrict__ out) {
    int blk = blockIdx.x;
    int bc = blk >> 2, qh = blk & 3;
    int b = bc >> 1;
    int tid = threadIdx.x;
    int h = qh * 256 + tid;
    __shared__ float aw[1024];
    for (int i = tid; i < 1024; i += 256) aw[i] = attw[bc * 1024 + i];
    __syncthreads();
    float acc = 0.f;
#pragma unroll 4
    for (int t = 0; t < 1024; ++t)
        acc += aw[t] * b2f(lstm_pad[((long)(b * 1026 + t + 1)) * 1024 + h]);
    out[bc * 1024 + h] = acc;
}

// ---------------------------------------------------------------------------
// Host orchestration
// ---------------------------------------------------------------------------
static void gemm_bt(hipStream_t st, const short* A, const short* B, float* Cf, short* Cb,
                    const float* bias, int M, int N, int K, int lda, int ldb, int ldc,
                    int z, int z0n, long sA0, long sA1, long sB0, long sB1, long sC0, long sC1,
                    int act, int gap) {
    dim3 grid(N / 128, M / 128, z);
    k_gemm_bt<<<grid, dim3(256), 0, st>>>(A, B, Cf, Cb, bias, M, N, K, lda, ldb, ldc,
                                          z0n, sA0, sA1, sB0, sB1, sC0, sC1, act, gap);
}

extern "C" void kernel_launch(void* const* d_in, const int* in_sizes, int n_in,
                              void* d_out, int out_size, void* d_ws, size_t ws_size,
                              hipStream_t stream) {
    if (ws_size < 199409920u) return;

    const float* x     = (const float*)d_in[0];
    const float* w_in1 = (const float*)d_in[1];
    const float* b_in1 = (const float*)d_in[2];
    const float* w_in2 = (const float*)d_in[3];
    const float* b_in2 = (const float*)d_in[4];
    const float* w_q   = (const float*)d_in[5];
    const float* b_q   = (const float*)d_in[6];
    const float* w_k   = (const float*)d_in[7];
    const float* b_k   = (const float*)d_in[8];
    const float* w_v   = (const float*)d_in[9];
    const float* b_v   = (const float*)d_in[10];
    const float* w_p   = (const float*)d_in[11];
    const float* b_p   = (const float*)d_in[12];
    const float* ln_g  = (const float*)d_in[13];
    const float* ln_b  = (const float*)d_in[14];
    const float* w_ih  = (const float*)d_in[15];
    const float* w_hh  = (const float*)d_in[16];
    const float* b_ih  = (const float*)d_in[17];
    const float* b_hh  = (const float*)d_in[18];
    const float* w_c1  = (const float*)d_in[19];
    const float* b_c1  = (const float*)d_in[20];
    const float* w_c2  = (const float*)d_in[21];
    const float* b_c2  = (const float*)d_in[22];

    char* ws = (char*)d_ws;
    // ---- static region ----
    short* w1b  = (short*)(ws + 0);
    short* w2b  = (short*)(ws + 524288);
    short* wqb  = (short*)(ws + 1048576);
    short* wkb  = (short*)(ws + 2097152);
    short* wvb  = (short*)(ws + 3145728);
    short* wpb  = (short*)(ws + 5242880);
    short* wihb = (short*)(ws + 7340032);
    short* whhb = (short*)(ws + 11534336);
    short* wc1b = (short*)(ws + 19922944);
    float* bsum = (float*)(ws + 23068672);
    short* hs0  = (short*)(ws + 23085056);     // 32 KB
    short* hs1  = (short*)(ws + 23117824);     // 32 KB
    int*   arr  = (int*)  (ws + 23150592);     // 512 B
    float* a2   = (float*)(ws + 23150848);
    short* lpad = (short*)(ws + 23216384);
    // ---- dynamic region D0 = 40,026,368 ----
    const size_t D0 = 40026368u;
    short* xbf   = (short*)(ws + D0);
    short* h1bf  = (short*)(ws + D0 + 8388608);
    short* h2bf  = (short*)(ws + D0 + 16777216);
    short* qbf   = (short*)(ws + D0 + 25165824);
    short* kbf   = (short*)(ws + D0 + 41943040);
    short* vbf   = (short*)(ws + D0 + 58720256);
    short* vTbf  = (short*)(ws + D0 + 92274688);
    short* scb   = (short*)(ws + D0);
    short* obf   = (short*)(ws + D0 + 125829120);
    short* ybf   = (short*)(ws + D0 + 58720256);
    short* ylnbf = (short*)(ws + D0 + 67108864);
    short* igb   = (short*)(ws + D0 + 92274688);
    short* a1bf  = (short*)(ws + D0);

    hipMemsetAsync(lpad, 0, (size_t)8 * 1026 * 1024 * 2, stream);
    hipMemsetAsync(hs0, 0, 32768, stream);
    hipMemsetAsync(hs1, 0, 32768, stream);
    hipMemsetAsync(arr, 0, 512, stream);

    k_f32_to_bf16<<<dim3(4096), dim3(256), 0, stream>>>(x, xbf, 8192 * 512);
    k_cvt_weights<<<dim3(4096), dim3(256), 0, stream>>>(w_in1, w_in2, w_q, w_k, w_v, w_p,
                                                        w_ih, w_hh, w1b);
    k_wc1_tr<<<dim3((512 * 3072 + 255) / 256), dim3(256), 0, stream>>>(w_c1, wc1b);
    k_bias_sum<<<dim3(16), dim3(256), 0, stream>>>(b_ih, b_hh, bsum, 4096);

    gemm_bt(stream, xbf, w1b, nullptr, h1bf, b_in1, 8192, 512, 512, 512, 512, 512,
            1, 1, 0, 0, 0, 0, 0, 0, 1, 0);
    gemm_bt(stream, h1bf, w2b, nullptr, h2bf, b_in2, 8192, 512, 512, 512, 512, 512,
            1, 1, 0, 0, 0, 0, 0, 0, 0, 0);
    gemm_bt(stream, h2bf, wqb, nullptr, qbf, b_q, 8192, 1024, 512, 512, 512, 1024,
            1, 1, 0, 0, 0, 0, 0, 0, 0, 0);
    gemm_bt(stream, h2bf, wkb, nullptr, kbf, b_k, 8192, 1024, 512, 512, 512, 1024,
            1, 1, 0, 0, 0, 0, 0, 0, 0, 0);
    gemm_bt(stream, h2bf, wvb, nullptr, vbf, b_v, 8192, 2048, 512, 512, 512, 2048,
            1, 1, 0, 0, 0, 0, 0, 0, 0, 0);
    k_vT<<<dim3(16, 32, 32), dim3(256), 0, stream>>>(vbf, vTbf);

    for (int bg = 0; bg < 4; ++bg) {
        const short* qb = qbf + (long)bg * 2097152;
        const short* kb = kbf + (long)bg * 2097152;
        gemm_bt(stream, qb, kb, nullptr, scb, nullptr, 1024, 1024, 256, 1024, 1024, 1024,
                8, 4, 256, 1048576, 256, 1048576, 1048576, 4194304, 0, 0);
        k_softmax_rows_bf16<<<dim3(8192), dim3(256), 0, stream>>>(scb);
        gemm_bt(stream, scb, vTbf + (long)bg * 4194304, nullptr, obf + (long)bg * 4194304, nullptr,
                1024, 512, 1024, 1024, 1024, 2048,
                8, 4, 1048576, 4194304, 524288, 2097152, 512, 2097152, 0, 0);
    }

    gemm_bt(stream, obf, wpb, nullptr, ybf, b_p, 8192, 512, 2048, 2048, 2048, 512,
            1, 1, 0, 0, 0, 0, 0, 0, 0, 0);
    k_layernorm<<<dim3(8192), dim3(256), 0, stream>>>(ybf, ln_g, ln_b, ylnbf);
    gemm_bt(stream, ylnbf, wihb, nullptr, igb, bsum, 8192, 4096, 512, 512, 512, 4096,
            1, 1, 0, 0, 0, 0, 0, 0, 0, 0);
    k_lstm<<<dim3(64), dim3(256), 0, stream>>>(whhb, igb, hs0, hs1, lpad, arr);
    gemm_bt(stream, lpad, wc1b, nullptr, a1bf, b_c1, 8192, 512, 3072, 1024, 3072, 512,
            1, 1, 0, 0, 0, 0, 0, 0, 2, 1);
    k_conv2<<<dim3(64), dim3(256), 0, stream>>>(a1bf, w_c2, b_c2, a2);
    k_softmax_rows_f32<<<dim3(16), dim3(256), 0, stream>>>(a2);
    k_feat<<<dim3(64), dim3(256), 0, stream>>>(a2, lpad, (float*)d_out);
    (void)in_sizes; (void)n_in; (void)out_size; (void)ws_size;
}